// Round 5
// baseline (784.574 us; speedup 1.0000x reference)
//
#include <hip/hip_runtime.h>

#define NN 50000
#define EE 1600000
#define DD 128
#define CC 10
#define LLAY 4
#define GG 512
#define GD (GG*DD)
#define NB 196           // ceil(NN/256) coarse buckets
#define BK_EDGES 6400    // edges per binA/bhist block
#define TILE 12500       // src-tile size (4 tiles; 12500*256B = 3.2MB < 4MB L2/XCD)

static constexpr float BN_EPS = 1e-5f;
static constexpr float INV_N = 1.0f / (float)NN;

typedef __bf16 bf16x8 __attribute__((ext_vector_type(8)));
typedef float f32x4 __attribute__((ext_vector_type(4)));

static __device__ __forceinline__ float bflo(unsigned u){ return __uint_as_float(u << 16); }
static __device__ __forceinline__ float bfhi(unsigned u){ return __uint_as_float(u & 0xffff0000u); }
static __device__ __forceinline__ unsigned short f2bf(float f){
    unsigned u = __float_as_uint(f);
    return (unsigned short)((u + 0x7fffu + ((u >> 16) & 1u)) >> 16);   // RNE
}
static __device__ __forceinline__ unsigned packbf(float a, float b){
    return (unsigned)f2bf(a) | ((unsigned)f2bf(b) << 16);
}
static __device__ __forceinline__ bf16x8 ldfrag(const unsigned short* p){
    union { uint4 u; bf16x8 b; } t; t.u = *(const uint4*)p; return t.b;
}

// ---------------- setup kernels ----------------

__global__ void zero_k(int* p, int n){
    int i = blockIdx.x * 256 + threadIdx.x;
    if (i < n) p[i] = 0;
}

// x (fp32) -> [n][64] packed bf16-pair layout
__global__ void convx_k(const float2* __restrict__ x2, unsigned* __restrict__ h32){
    int i = blockIdx.x * 256 + threadIdx.x;   // grid covers NN*64 exactly
    float2 v = x2[i];
    h32[i] = packbf(v.x, v.y);
}

// all 8 weight matrices -> bf16 W^T [j][k] in ws
__global__ void wprep_k(const float* __restrict__ W1, const float* __restrict__ W2,
                        unsigned short* __restrict__ Wtall){
    int idx = blockIdx.x * 256 + threadIdx.x;         // < 8*16384
    int mat = idx >> 14; int rr = idx & 16383;
    int k = rr >> 7; int j = rr & 127;
    const float* Wsrc = (mat < 4) ? (W1 + mat * 16384) : (W2 + (mat - 4) * 16384);
    Wtall[mat * 16384 + j * 128 + k] = f2bf(Wsrc[k * 128 + j]);
}

// bucket-level histogram (196 buckets of 256 dst nodes)
__global__ __launch_bounds__(256) void bhist_k(const int* __restrict__ dstA,
                                               int* __restrict__ bucketCnt){
    __shared__ int c[NB];
    int tid = threadIdx.x;
    if (tid < NB) c[tid] = 0;
    __syncthreads();
    int e0 = blockIdx.x * BK_EDGES;
    for (int i = tid; i < BK_EDGES; i += 256){
        int e = e0 + i;
        if (e < EE) atomicAdd(&c[dstA[e] >> 8], 1);
    }
    __syncthreads();
    if (tid < NB && c[tid] > 0) atomicAdd(&bucketCnt[tid], c[tid]);
}

// scan bucket counts -> bucketBase / bucketCur; also terminal rp4 entry
__global__ __launch_bounds__(256) void bscan_k(const int* __restrict__ bucketCnt,
                                               int* __restrict__ bucketBase,
                                               int* __restrict__ bucketCur,
                                               int* __restrict__ rp4){
    __shared__ int lds[256];
    int t = threadIdx.x;
    int v = (t < NB) ? bucketCnt[t] : 0;
    lds[t] = v; __syncthreads();
    for (int o = 1; o < 256; o <<= 1){
        int xv = 0; if (t >= o) xv = lds[t - o];
        __syncthreads(); lds[t] += xv; __syncthreads();
    }
    int excl = lds[t] - v;
    if (t < NB){ bucketBase[t] = excl; bucketCur[t] = excl; }
    if (t == 0){ bucketBase[NB] = EE; rp4[NN * 4] = EE; }
}

// graph boundaries via binary search on sorted batch
__global__ void gsearch_k(const int* __restrict__ batch, int* __restrict__ gstart){
    int g = blockIdx.x * 256 + threadIdx.x;
    if (g <= GG){
        int lo = 0, hi = NN;
        while (lo < hi){ int mid = (lo + hi) >> 1; if (batch[mid] < g) lo = mid + 1; else hi = mid; }
        gstart[g] = lo;
    }
}

// Pass A: bin edges into NB coarse buckets, contiguous runs.
__global__ __launch_bounds__(256) void binA_k(const int* __restrict__ srcA,
                                              const int* __restrict__ dstA,
                                              int* __restrict__ bucketCur,
                                              unsigned* __restrict__ binned){
    __shared__ int cnt[NB], bas[NB], off[NB];
    int tid = threadIdx.x;
    if (tid < NB){ cnt[tid] = 0; off[tid] = 0; }
    __syncthreads();
    int e0 = blockIdx.x * BK_EDGES;
    for (int i = tid; i < BK_EDGES; i += 256){
        int e = e0 + i;
        if (e < EE) atomicAdd(&cnt[dstA[e] >> 8], 1);
    }
    __syncthreads();
    if (tid < NB && cnt[tid] > 0) bas[tid] = atomicAdd(&bucketCur[tid], cnt[tid]);
    __syncthreads();
    for (int i = tid; i < BK_EDGES; i += 256){
        int e = e0 + i;
        if (e < EE){
            int d = dstA[e]; int b = d >> 8;
            int p = bas[b] + atomicAdd(&off[b], 1);
            binned[p] = (unsigned)srcA[e] | ((unsigned)(d & 255) << 17);  // src<2^17
        }
    }
}

// Pass B: per-bucket (node, src-tile) counts -> rp4 + exact placement.
__global__ __launch_bounds__(256) void binB_k(const unsigned* __restrict__ binned,
                                              const int* __restrict__ bucketBase,
                                              int* __restrict__ rp4,
                                              int* __restrict__ ssort){
    __shared__ int c4[1024];
    __shared__ int b4[1024];
    __shared__ int nt[256];
    int b = blockIdx.x, tid = threadIdx.x;
    int nb0 = b * 256;
    int nmax = NN - nb0; if (nmax > 256) nmax = 256;
    c4[tid] = 0; c4[256 + tid] = 0; c4[512 + tid] = 0; c4[768 + tid] = 0;
    __syncthreads();
    int base = bucketBase[b];
    int end  = bucketBase[b + 1];
    for (int i = base + tid; i < end; i += 256){
        unsigned u = binned[i];
        int src = (int)(u & 0x1FFFFu); int dl = (int)(u >> 17);
        int t = (src >= TILE) + (src >= 2 * TILE) + (src >= 3 * TILE);
        atomicAdd(&c4[dl * 4 + t], 1);
    }
    __syncthreads();
    int c0 = c4[tid * 4], c1 = c4[tid * 4 + 1], c2 = c4[tid * 4 + 2], c3 = c4[tid * 4 + 3];
    int tot = c0 + c1 + c2 + c3;
    nt[tid] = tot; __syncthreads();
    for (int o = 1; o < 256; o <<= 1){
        int xv = 0; if (tid >= o) xv = nt[tid - o];
        __syncthreads(); nt[tid] += xv; __syncthreads();
    }
    int p = base + nt[tid] - tot;
    b4[tid * 4] = p; b4[tid * 4 + 1] = p + c0;
    b4[tid * 4 + 2] = p + c0 + c1; b4[tid * 4 + 3] = p + c0 + c1 + c2;
    if (tid < nmax){
        int n = nb0 + tid;
        rp4[n * 4]     = b4[tid * 4];     rp4[n * 4 + 1] = b4[tid * 4 + 1];
        rp4[n * 4 + 2] = b4[tid * 4 + 2]; rp4[n * 4 + 3] = b4[tid * 4 + 3];
    }
    __syncthreads();
    c4[tid] = 0; c4[256 + tid] = 0; c4[512 + tid] = 0; c4[768 + tid] = 0;
    __syncthreads();
    for (int i = base + tid; i < end; i += 256){
        unsigned u = binned[i];
        int src = (int)(u & 0x1FFFFu); int dl = (int)(u >> 17);
        int t = (src >= TILE) + (src >= 2 * TILE) + (src >= 3 * TILE);
        int pos = b4[dl * 4 + t] + atomicAdd(&c4[dl * 4 + t], 1);
        ssort[pos] = src;
    }
}

// ---------------- per-layer kernels ----------------

// src-tiled aggregation pass t: zf += sum over sublist t; t==0 seeds with h[n],
// t==3 finalizes to packed bf16 z32. Gathers stay within one 3.2MB tile -> L2.
__global__ __launch_bounds__(256) void aggT_k(const unsigned* __restrict__ h32,
                                              const int* __restrict__ rp4,
                                              const int* __restrict__ ssort,
                                              float2* __restrict__ zf,
                                              unsigned* __restrict__ z32,
                                              float* __restrict__ zstats, int t){
    int tid = threadIdx.x;
    if (t == 0 && blockIdx.x == 0) zstats[tid] = 0.f;
    int n = blockIdx.x * 4 + (tid >> 6);  // grid*4 == NN exactly
    int lane = tid & 63;
    float ax, ay;
    if (t == 0){
        unsigned self = h32[n * 64 + lane];
        ax = bflo(self); ay = bfhi(self);
    } else {
        float2 v = zf[n * 64 + lane];
        ax = v.x; ay = v.y;
    }
    int e  = __builtin_amdgcn_readfirstlane(rp4[n * 4 + t]);
    int e1 = __builtin_amdgcn_readfirstlane(rp4[n * 4 + t + 1]);
    for (; e + 3 < e1; e += 4){
        int s0 = ssort[e], s1 = ssort[e + 1], s2 = ssort[e + 2], s3 = ssort[e + 3];
        unsigned u0 = h32[s0 * 64 + lane];
        unsigned u1 = h32[s1 * 64 + lane];
        unsigned u2 = h32[s2 * 64 + lane];
        unsigned u3 = h32[s3 * 64 + lane];
        ax += bflo(u0) + bflo(u1); ay += bfhi(u0) + bfhi(u1);
        ax += bflo(u2) + bflo(u3); ay += bfhi(u2) + bfhi(u3);
    }
    for (; e < e1; ++e){
        unsigned u0 = h32[ssort[e] * 64 + lane];
        ax += bflo(u0); ay += bfhi(u0);
    }
    if (t < 3) zf[n * 64 + lane] = make_float2(ax, ay);
    else       z32[n * 64 + lane] = packbf(ax, ay);
}

// C[N,128] = opt_relu_bn(A[N,128]) @ W[128,128] + bias, bf16 MFMA 16x16x32.
// Fused epilogue: column sum/sumsq of fp32 C -> atomicAdd into ostats.
template<int TR>
__global__ __launch_bounds__(256) void gemm_k(const unsigned* __restrict__ A32,
                                              const unsigned short* __restrict__ Wtg,
                                              const float* __restrict__ bias,
                                              unsigned short* __restrict__ Cst,
                                              const float* __restrict__ stats,
                                              const float* __restrict__ gma,
                                              const float* __restrict__ bta,
                                              float* __restrict__ ostats,
                                              float* __restrict__ zstats){
    __shared__ __align__(16) unsigned short Wl[128 * 128];  // [j][k] 32KB
    __shared__ __align__(16) unsigned short As[128 * 64];   // [row][k-half] 16KB (reused as f32 scratch)
    __shared__ float sl[128], tl[128];
    int tid = threadIdx.x;
    if (blockIdx.x == 0 && zstats) zstats[tid] = 0.f;
    {
        const uint4* src = (const uint4*)Wtg; uint4* dst = (uint4*)Wl;
        #pragma unroll
        for (int i = 0; i < 8; i++) dst[tid + 256 * i] = src[tid + 256 * i];
    }
    if (TR && tid < 128){
        float mean = stats[tid] * INV_N;
        float q    = stats[128 + tid] * INV_N;
        float inv  = rsqrtf(q - mean * mean + BN_EPS);
        float s    = gma[tid] * inv;
        sl[tid] = s; tl[tid] = bta[tid] - mean * s;
    }
    __syncthreads();

    f32x4 acc[2][8];
    #pragma unroll
    for (int a = 0; a < 2; a++)
        #pragma unroll
        for (int b = 0; b < 8; b++) acc[a][b] = (f32x4){0.f, 0.f, 0.f, 0.f};

    int wv = tid >> 6, lane = tid & 63;
    int rowbase = blockIdx.x * 128;
    int r = tid >> 1, koU = (tid & 1) * 16;

    for (int kh = 0; kh < 2; ++kh){
        if (kh) __syncthreads();
        uint4 v[4];
        int grow = rowbase + r;
        if (grow < NN){
            const uint4* p = (const uint4*)(A32 + grow * 64 + kh * 32 + koU);
            #pragma unroll
            for (int j = 0; j < 4; j++) v[j] = p[j];
        } else {
            #pragma unroll
            for (int j = 0; j < 4; j++) v[j] = make_uint4(0, 0, 0, 0);
        }
        if (TR){
            #pragma unroll
            for (int j = 0; j < 4; j++){
                unsigned* pu = (unsigned*)&v[j];
                #pragma unroll
                for (int c = 0; c < 4; c++){
                    int k = kh * 64 + koU * 2 + j * 8 + c * 2;
                    float f0 = fmaxf(bflo(pu[c]) * sl[k] + tl[k], 0.f);
                    float f1 = fmaxf(bfhi(pu[c]) * sl[k + 1] + tl[k + 1], 0.f);
                    pu[c] = packbf(f0, f1);
                }
            }
        }
        {
            uint4* dst = ((uint4*)As) + r * 8 + (tid & 1) * 4;
            #pragma unroll
            for (int j = 0; j < 4; j++) dst[j] = v[j];
        }
        __syncthreads();
        #pragma unroll
        for (int kc = 0; kc < 2; ++kc){
            int kof = kc * 32 + ((lane >> 4) * 8);
            bf16x8 a0 = ldfrag(&As[(wv * 32 +      (lane & 15)) * 64 + kof]);
            bf16x8 a1 = ldfrag(&As[(wv * 32 + 16 + (lane & 15)) * 64 + kof]);
            int wk = kh * 64 + kof;
            #pragma unroll
            for (int ct = 0; ct < 8; ++ct){
                bf16x8 b = ldfrag(&Wl[(ct * 16 + (lane & 15)) * 128 + wk]);
                acc[0][ct] = __builtin_amdgcn_mfma_f32_16x16x32_bf16(a0, b, acc[0][ct], 0, 0, 0);
                acc[1][ct] = __builtin_amdgcn_mfma_f32_16x16x32_bf16(a1, b, acc[1][ct], 0, 0, 0);
            }
        }
    }
    // epilogue: C/D layout col=lane&15, row=(lane>>4)*4+reg. Store + column stats.
    int cl = lane & 15, rq = lane >> 4;
    float colS[8], colQ[8];
    #pragma unroll
    for (int ct = 0; ct < 8; ++ct){
        float bv = bias[ct * 16 + cl];
        float ps = 0.f, pq = 0.f;
        #pragma unroll
        for (int rt = 0; rt < 2; ++rt){
            #pragma unroll
            for (int rr2 = 0; rr2 < 4; ++rr2){
                int grow = rowbase + wv * 32 + rt * 16 + rq * 4 + rr2;
                if (grow < NN){
                    float val = acc[rt][ct][rr2] + bv;
                    Cst[grow * 128 + ct * 16 + cl] = f2bf(val);
                    ps += val; pq += val * val;
                }
            }
        }
        ps += __shfl_xor(ps, 16); pq += __shfl_xor(pq, 16);
        ps += __shfl_xor(ps, 32); pq += __shfl_xor(pq, 32);
        colS[ct] = ps; colQ[ct] = pq;
    }
    __syncthreads();                       // done with As; reuse as float scratch
    float* sred = (float*)As;              // [0..511]=sums(wv,col), [512..1023]=sumsq
    if (rq == 0){
        #pragma unroll
        for (int ct = 0; ct < 8; ++ct){
            sred[wv * 128 + ct * 16 + cl]       = colS[ct];
            sred[512 + wv * 128 + ct * 16 + cl] = colQ[ct];
        }
    }
    __syncthreads();
    if (tid < 128){
        float s1 = sred[tid] + sred[128 + tid] + sred[256 + tid] + sred[384 + tid];
        float s2 = sred[512 + tid] + sred[640 + tid] + sred[768 + tid] + sred[896 + tid];
        atomicAdd(&ostats[tid], s1);
        atomicAdd(&ostats[128 + tid], s2);
    }
}

// h = relu(bn(z)) (write h) fused with per-graph pooling. One block per graph.
__global__ __launch_bounds__(256) void ewpool_k(const unsigned* __restrict__ z32,
                                                const float* __restrict__ stats,
                                                const float* __restrict__ g,
                                                const float* __restrict__ b,
                                                const int* __restrict__ gstart,
                                                unsigned* __restrict__ h32,
                                                float* __restrict__ outp){
    __shared__ float sd[512];
    int gid = blockIdx.x; int tid = threadIdx.x;
    int c = tid & 63, rs = tid >> 6;
    int c2 = c * 2;
    float m0 = stats[c2] * INV_N,     q0 = stats[128 + c2] * INV_N;
    float inv0 = rsqrtf(q0 - m0 * m0 + BN_EPS);
    float s0 = g[c2] * inv0, t0 = b[c2] - m0 * s0;
    float m1 = stats[c2 + 1] * INV_N, q1 = stats[129 + c2] * INV_N;
    float inv1 = rsqrtf(q1 - m1 * m1 + BN_EPS);
    float s1 = g[c2 + 1] * inv1, t1 = b[c2 + 1] - m1 * s1;
    int s = gstart[gid], e = gstart[gid + 1];
    float a0 = 0.f, a1 = 0.f;
    for (int n = s + rs; n < e; n += 4){
        unsigned u = z32[n * 64 + c];
        float f0 = fmaxf(bflo(u) * s0 + t0, 0.f);
        float f1 = fmaxf(bfhi(u) * s1 + t1, 0.f);
        h32[n * 64 + c] = packbf(f0, f1);
        a0 += f0; a1 += f1;
    }
    sd[tid] = a0; sd[256 + tid] = a1; __syncthreads();
    if (tid < 64){
        float r0 = 0.f, r1 = 0.f;
        #pragma unroll
        for (int k2 = 0; k2 < 4; k2++){ r0 += sd[tid + 64 * k2]; r1 += sd[256 + tid + 64 * k2]; }
        outp[gid * 128 + 2 * tid] = r0; outp[gid * 128 + 2 * tid + 1] = r1;
    }
}

// pooled[0] from fp32 x (exact)
__global__ __launch_bounds__(256) void poolx_k(const float* __restrict__ x,
                                               const int* __restrict__ gstart,
                                               float* __restrict__ outp){
    __shared__ float sd[256];
    int g = blockIdx.x; int tid = threadIdx.x; int c = tid & 127, rs = tid >> 7;
    int s = gstart[g], e = gstart[g + 1];
    float a = 0;
    for (int n = s + rs; n < e; n += 2) a += x[n * 128 + c];
    sd[tid] = a; __syncthreads();
    if (tid < 128) outp[g * 128 + tid] = sd[tid] + sd[tid + 128];
}

// logits = sum_i pooled_i @ fcW_i + fcb_i ; out = log_softmax(logits)
__global__ __launch_bounds__(64) void final_k(const float* __restrict__ pooled,
                                              const float* __restrict__ fcW,
                                              const float* __restrict__ fcb,
                                              float* __restrict__ out){
    int g = blockIdx.x, l = threadIdx.x;
    float p0[5], p1[5];
    #pragma unroll
    for (int i = 0; i < 5; i++){
        p0[i] = pooled[i * GD + g * 128 + l];
        p1[i] = pooled[i * GD + g * 128 + 64 + l];
    }
    float lg[10];
    #pragma unroll
    for (int c2 = 0; c2 < 10; c2++){
        float s = 0;
        #pragma unroll
        for (int i = 0; i < 5; i++){
            s += p0[i] * fcW[(i * 128 + l) * 10 + c2];
            s += p1[i] * fcW[(i * 128 + 64 + l) * 10 + c2];
        }
        #pragma unroll
        for (int off = 32; off >= 1; off >>= 1) s += __shfl_down(s, off);
        lg[c2] = s;
    }
    if (l == 0){
        #pragma unroll
        for (int c2 = 0; c2 < 10; c2++){
            float bs = 0;
            #pragma unroll
            for (int i = 0; i < 5; i++) bs += fcb[i * 10 + c2];
            lg[c2] += bs;
        }
        float mx = lg[0];
        #pragma unroll
        for (int c2 = 1; c2 < 10; c2++) mx = fmaxf(mx, lg[c2]);
        float se = 0;
        #pragma unroll
        for (int c2 = 0; c2 < 10; c2++) se += expf(lg[c2] - mx);
        float lse = mx + logf(se);
        #pragma unroll
        for (int c2 = 0; c2 < 10; c2++) out[g * 10 + c2] = lg[c2] - lse;
    }
}

// ---------------- launch ----------------

extern "C" void kernel_launch(void* const* d_in, const int* in_sizes, int n_in,
                              void* d_out, int out_size, void* d_ws, size_t ws_size,
                              hipStream_t stream){
    (void)in_sizes; (void)n_in; (void)out_size; (void)ws_size;
    const float* x     = (const float*)d_in[0];
    const int*   ei    = (const int*)d_in[1];
    const int*   batch = (const int*)d_in[2];
    const float* cW1   = (const float*)d_in[4];
    const float* cb1   = (const float*)d_in[5];
    const float* cbng  = (const float*)d_in[6];
    const float* cbnb  = (const float*)d_in[7];
    const float* cW2   = (const float*)d_in[8];
    const float* cb2   = (const float*)d_in[9];
    const float* bng   = (const float*)d_in[10];
    const float* bnb   = (const float*)d_in[11];
    const float* fcW   = (const float*)d_in[12];
    const float* fcb   = (const float*)d_in[13];

    char* base = (char*)d_ws;
    size_t off = 0;
    auto alloc = [&](size_t bytes) -> void* {
        void* p = base + off;
        off = (off + bytes + 255) & ~(size_t)255;
        return p;
    };
    unsigned*       hB     = (unsigned*)alloc((size_t)NN * 64 * 4);
    unsigned*       zA     = (unsigned*)alloc((size_t)NN * 64 * 4);
    unsigned*       zB     = (unsigned*)alloc((size_t)NN * 64 * 4);
    float2*         zf     = (float2*)alloc((size_t)NN * 64 * 8);    // fp32 partial sums
    unsigned short* Wtall  = (unsigned short*)alloc(8 * 16384 * 2);
    int*            ssort  = (int*)alloc((size_t)EE * 4);
    int*            rp4    = (int*)alloc(((size_t)NN * 4 + 1) * 4);
    int*            gstart = (int*)alloc((GG + 1) * 4);
    int*            bucketCnt  = (int*)alloc(NB * 4);
    int*            bucketBase = (int*)alloc((NB + 1) * 4);
    int*            bucketCur  = (int*)alloc(NB * 4);
    float*          pooled = (float*)alloc((size_t)5 * GD * 4);
    float*          stats1 = (float*)alloc(256 * 4);
    float*          stats2 = (float*)alloc(256 * 4);
    unsigned*       binned = (unsigned*)zf;   // alias: binned only used before layer loop

    zero_k<<<1, 256, 0, stream>>>(bucketCnt, NB);
    convx_k<<<NN * 64 / 256, 256, 0, stream>>>((const float2*)x, hB);
    wprep_k<<<512, 256, 0, stream>>>(cW1, cW2, Wtall);
    bhist_k<<<(EE + BK_EDGES - 1) / BK_EDGES, 256, 0, stream>>>(ei + EE, bucketCnt);
    bscan_k<<<1, 256, 0, stream>>>(bucketCnt, bucketBase, bucketCur, rp4);
    gsearch_k<<<3, 256, 0, stream>>>(batch, gstart);
    binA_k<<<(EE + BK_EDGES - 1) / BK_EDGES, 256, 0, stream>>>(ei, ei + EE, bucketCur, binned);
    binB_k<<<NB, 256, 0, stream>>>(binned, bucketBase, rp4, ssort);
    poolx_k<<<GG, 256, 0, stream>>>(x, gstart, pooled);

    const int gemmGrid = (NN + 127) / 128;
    for (int i = 0; i < LLAY; i++){
        for (int t = 0; t < 4; t++)
            aggT_k<<<NN / 4, 256, 0, stream>>>(hB, rp4, ssort, zf, zA, stats1, t);
        gemm_k<0><<<gemmGrid, 256, 0, stream>>>(zA, Wtall + i * 16384, cb1 + i * 128,
                                                (unsigned short*)zB,
                                                nullptr, nullptr, nullptr, stats1, stats2);
        gemm_k<1><<<gemmGrid, 256, 0, stream>>>(zB, Wtall + (4 + i) * 16384, cb2 + i * 128,
                                                (unsigned short*)zA,
                                                stats1, cbng + i * 128, cbnb + i * 128, stats2, nullptr);
        ewpool_k<<<GG, 256, 0, stream>>>(zA, stats2, bng + i * 128, bnb + i * 128,
                                         gstart, hB, pooled + (size_t)(i + 1) * GD);
    }
    final_k<<<GG, 64, 0, stream>>>(pooled, fcW, fcb, (float*)d_out);
}

// Round 6
// 639.485 us; speedup vs baseline: 1.2269x; 1.2269x over previous
//
#include <hip/hip_runtime.h>

#define NN 50000
#define EE 1600000
#define DD 128
#define CC 10
#define LLAY 4
#define GG 512
#define GD (GG*DD)
#define NB 196           // ceil(NN/256) coarse buckets
#define BK_EDGES 6400    // edges per binA/bhist block
#define TILE 12500       // src-tile split kept in binB (harmless sub-ordering)

static constexpr float BN_EPS = 1e-5f;
static constexpr float INV_N = 1.0f / (float)NN;

typedef __bf16 bf16x8 __attribute__((ext_vector_type(8)));
typedef float f32x4 __attribute__((ext_vector_type(4)));

static __device__ __forceinline__ float bflo(unsigned u){ return __uint_as_float(u << 16); }
static __device__ __forceinline__ float bfhi(unsigned u){ return __uint_as_float(u & 0xffff0000u); }
static __device__ __forceinline__ unsigned short f2bf(float f){
    unsigned u = __float_as_uint(f);
    return (unsigned short)((u + 0x7fffu + ((u >> 16) & 1u)) >> 16);   // RNE
}
static __device__ __forceinline__ unsigned packbf(float a, float b){
    return (unsigned)f2bf(a) | ((unsigned)f2bf(b) << 16);
}
static __device__ __forceinline__ bf16x8 ldfrag(const unsigned short* p){
    union { uint4 u; bf16x8 b; } t; t.u = *(const uint4*)p; return t.b;
}

// ---------------- setup kernels ----------------

__global__ void zero_k(int* p, int n){
    int i = blockIdx.x * 256 + threadIdx.x;
    if (i < n) p[i] = 0;
}

// x (fp32) -> [n][64] packed bf16-pair layout
__global__ void convx_k(const float2* __restrict__ x2, unsigned* __restrict__ h32){
    int i = blockIdx.x * 256 + threadIdx.x;   // grid covers NN*64 exactly
    float2 v = x2[i];
    h32[i] = packbf(v.x, v.y);
}

// all 8 weight matrices -> bf16 W^T [j][k] in ws
__global__ void wprep_k(const float* __restrict__ W1, const float* __restrict__ W2,
                        unsigned short* __restrict__ Wtall){
    int idx = blockIdx.x * 256 + threadIdx.x;         // < 8*16384
    int mat = idx >> 14; int rr = idx & 16383;
    int k = rr >> 7; int j = rr & 127;
    const float* Wsrc = (mat < 4) ? (W1 + mat * 16384) : (W2 + (mat - 4) * 16384);
    Wtall[mat * 16384 + j * 128 + k] = f2bf(Wsrc[k * 128 + j]);
}

// bucket-level histogram (196 buckets of 256 dst nodes)
__global__ __launch_bounds__(256) void bhist_k(const int* __restrict__ dstA,
                                               int* __restrict__ bucketCnt){
    __shared__ int c[NB];
    int tid = threadIdx.x;
    if (tid < NB) c[tid] = 0;
    __syncthreads();
    int e0 = blockIdx.x * BK_EDGES;
    for (int i = tid; i < BK_EDGES; i += 256){
        int e = e0 + i;
        if (e < EE) atomicAdd(&c[dstA[e] >> 8], 1);
    }
    __syncthreads();
    if (tid < NB && c[tid] > 0) atomicAdd(&bucketCnt[tid], c[tid]);
}

// scan bucket counts -> bucketBase / bucketCur; also terminal rp4 entry
__global__ __launch_bounds__(256) void bscan_k(const int* __restrict__ bucketCnt,
                                               int* __restrict__ bucketBase,
                                               int* __restrict__ bucketCur,
                                               int* __restrict__ rp4){
    __shared__ int lds[256];
    int t = threadIdx.x;
    int v = (t < NB) ? bucketCnt[t] : 0;
    lds[t] = v; __syncthreads();
    for (int o = 1; o < 256; o <<= 1){
        int xv = 0; if (t >= o) xv = lds[t - o];
        __syncthreads(); lds[t] += xv; __syncthreads();
    }
    int excl = lds[t] - v;
    if (t < NB){ bucketBase[t] = excl; bucketCur[t] = excl; }
    if (t == 0){ bucketBase[NB] = EE; rp4[NN * 4] = EE; }
}

// graph boundaries via binary search on sorted batch
__global__ void gsearch_k(const int* __restrict__ batch, int* __restrict__ gstart){
    int g = blockIdx.x * 256 + threadIdx.x;
    if (g <= GG){
        int lo = 0, hi = NN;
        while (lo < hi){ int mid = (lo + hi) >> 1; if (batch[mid] < g) lo = mid + 1; else hi = mid; }
        gstart[g] = lo;
    }
}

// Pass A: bin edges into NB coarse buckets, contiguous runs.
__global__ __launch_bounds__(256) void binA_k(const int* __restrict__ srcA,
                                              const int* __restrict__ dstA,
                                              int* __restrict__ bucketCur,
                                              unsigned* __restrict__ binned){
    __shared__ int cnt[NB], bas[NB], off[NB];
    int tid = threadIdx.x;
    if (tid < NB){ cnt[tid] = 0; off[tid] = 0; }
    __syncthreads();
    int e0 = blockIdx.x * BK_EDGES;
    for (int i = tid; i < BK_EDGES; i += 256){
        int e = e0 + i;
        if (e < EE) atomicAdd(&cnt[dstA[e] >> 8], 1);
    }
    __syncthreads();
    if (tid < NB && cnt[tid] > 0) bas[tid] = atomicAdd(&bucketCur[tid], cnt[tid]);
    __syncthreads();
    for (int i = tid; i < BK_EDGES; i += 256){
        int e = e0 + i;
        if (e < EE){
            int d = dstA[e]; int b = d >> 8;
            int p = bas[b] + atomicAdd(&off[b], 1);
            binned[p] = (unsigned)srcA[e] | ((unsigned)(d & 255) << 17);  // src<2^17
        }
    }
}

// Pass B: per-bucket (node, src-tile) counts -> rp4 + exact placement.
__global__ __launch_bounds__(256) void binB_k(const unsigned* __restrict__ binned,
                                              const int* __restrict__ bucketBase,
                                              int* __restrict__ rp4,
                                              int* __restrict__ ssort){
    __shared__ int c4[1024];
    __shared__ int b4[1024];
    __shared__ int nt[256];
    int b = blockIdx.x, tid = threadIdx.x;
    int nb0 = b * 256;
    int nmax = NN - nb0; if (nmax > 256) nmax = 256;
    c4[tid] = 0; c4[256 + tid] = 0; c4[512 + tid] = 0; c4[768 + tid] = 0;
    __syncthreads();
    int base = bucketBase[b];
    int end  = bucketBase[b + 1];
    for (int i = base + tid; i < end; i += 256){
        unsigned u = binned[i];
        int src = (int)(u & 0x1FFFFu); int dl = (int)(u >> 17);
        int t = (src >= TILE) + (src >= 2 * TILE) + (src >= 3 * TILE);
        atomicAdd(&c4[dl * 4 + t], 1);
    }
    __syncthreads();
    int c0 = c4[tid * 4], c1 = c4[tid * 4 + 1], c2 = c4[tid * 4 + 2], c3 = c4[tid * 4 + 3];
    int tot = c0 + c1 + c2 + c3;
    nt[tid] = tot; __syncthreads();
    for (int o = 1; o < 256; o <<= 1){
        int xv = 0; if (tid >= o) xv = nt[tid - o];
        __syncthreads(); nt[tid] += xv; __syncthreads();
    }
    int p = base + nt[tid] - tot;
    b4[tid * 4] = p; b4[tid * 4 + 1] = p + c0;
    b4[tid * 4 + 2] = p + c0 + c1; b4[tid * 4 + 3] = p + c0 + c1 + c2;
    if (tid < nmax){
        int n = nb0 + tid;
        rp4[n * 4]     = b4[tid * 4];     rp4[n * 4 + 1] = b4[tid * 4 + 1];
        rp4[n * 4 + 2] = b4[tid * 4 + 2]; rp4[n * 4 + 3] = b4[tid * 4 + 3];
    }
    __syncthreads();
    c4[tid] = 0; c4[256 + tid] = 0; c4[512 + tid] = 0; c4[768 + tid] = 0;
    __syncthreads();
    for (int i = base + tid; i < end; i += 256){
        unsigned u = binned[i];
        int src = (int)(u & 0x1FFFFu); int dl = (int)(u >> 17);
        int t = (src >= TILE) + (src >= 2 * TILE) + (src >= 3 * TILE);
        int pos = b4[dl * 4 + t] + atomicAdd(&c4[dl * 4 + t], 1);
        ssort[pos] = src;
    }
}

// ---------------- per-layer kernels ----------------

// z = h + sum_{in-edges} h[src]  (single pass; full range = [rp4[4n], rp4[4n+4]))
__global__ __launch_bounds__(256) void agg_k(const unsigned* __restrict__ h32,
                                             const int* __restrict__ rp4,
                                             const int* __restrict__ ssort,
                                             unsigned* __restrict__ z32,
                                             float* __restrict__ zstats){
    int tid = threadIdx.x;
    if (blockIdx.x == 0) zstats[tid] = 0.f;
    int n = blockIdx.x * 4 + (tid >> 6);  // grid*4 == NN exactly
    int lane = tid & 63;
    unsigned self = h32[n * 64 + lane];
    float ax = bflo(self), ay = bfhi(self);
    int e  = __builtin_amdgcn_readfirstlane(rp4[n * 4]);
    int e1 = __builtin_amdgcn_readfirstlane(rp4[n * 4 + 4]);
    for (; e + 7 < e1; e += 8){
        int s0 = ssort[e],     s1 = ssort[e + 1], s2 = ssort[e + 2], s3 = ssort[e + 3];
        int s4 = ssort[e + 4], s5 = ssort[e + 5], s6 = ssort[e + 6], s7 = ssort[e + 7];
        unsigned u0 = h32[s0 * 64 + lane];
        unsigned u1 = h32[s1 * 64 + lane];
        unsigned u2 = h32[s2 * 64 + lane];
        unsigned u3 = h32[s3 * 64 + lane];
        unsigned u4 = h32[s4 * 64 + lane];
        unsigned u5 = h32[s5 * 64 + lane];
        unsigned u6 = h32[s6 * 64 + lane];
        unsigned u7 = h32[s7 * 64 + lane];
        ax += bflo(u0) + bflo(u1); ay += bfhi(u0) + bfhi(u1);
        ax += bflo(u2) + bflo(u3); ay += bfhi(u2) + bfhi(u3);
        ax += bflo(u4) + bflo(u5); ay += bfhi(u4) + bfhi(u5);
        ax += bflo(u6) + bflo(u7); ay += bfhi(u6) + bfhi(u7);
    }
    for (; e < e1; ++e){
        unsigned u0 = h32[ssort[e] * 64 + lane];
        ax += bflo(u0); ay += bfhi(u0);
    }
    z32[n * 64 + lane] = packbf(ax, ay);
}

// C[N,128] = opt_relu_bn(A[N,128]) @ W[128,128] + bias, bf16 MFMA 16x16x32.
// Fused epilogue: column sum/sumsq of fp32 C -> atomicAdd into ostats.
template<int TR>
__global__ __launch_bounds__(256) void gemm_k(const unsigned* __restrict__ A32,
                                              const unsigned short* __restrict__ Wtg,
                                              const float* __restrict__ bias,
                                              unsigned short* __restrict__ Cst,
                                              const float* __restrict__ stats,
                                              const float* __restrict__ gma,
                                              const float* __restrict__ bta,
                                              float* __restrict__ ostats,
                                              float* __restrict__ zstats){
    __shared__ __align__(16) unsigned short Wl[128 * 128];  // [j][k] 32KB
    __shared__ __align__(16) unsigned short As[128 * 64];   // [row][k-half] 16KB (reused as f32 scratch)
    __shared__ float sl[128], tl[128];
    int tid = threadIdx.x;
    if (blockIdx.x == 0 && zstats) zstats[tid] = 0.f;
    {
        const uint4* src = (const uint4*)Wtg; uint4* dst = (uint4*)Wl;
        #pragma unroll
        for (int i = 0; i < 8; i++) dst[tid + 256 * i] = src[tid + 256 * i];
    }
    if (TR && tid < 128){
        float mean = stats[tid] * INV_N;
        float q    = stats[128 + tid] * INV_N;
        float inv  = rsqrtf(q - mean * mean + BN_EPS);
        float s    = gma[tid] * inv;
        sl[tid] = s; tl[tid] = bta[tid] - mean * s;
    }
    __syncthreads();

    f32x4 acc[2][8];
    #pragma unroll
    for (int a = 0; a < 2; a++)
        #pragma unroll
        for (int b = 0; b < 8; b++) acc[a][b] = (f32x4){0.f, 0.f, 0.f, 0.f};

    int wv = tid >> 6, lane = tid & 63;
    int rowbase = blockIdx.x * 128;
    int r = tid >> 1, koU = (tid & 1) * 16;

    for (int kh = 0; kh < 2; ++kh){
        if (kh) __syncthreads();
        uint4 v[4];
        int grow = rowbase + r;
        if (grow < NN){
            const uint4* p = (const uint4*)(A32 + grow * 64 + kh * 32 + koU);
            #pragma unroll
            for (int j = 0; j < 4; j++) v[j] = p[j];
        } else {
            #pragma unroll
            for (int j = 0; j < 4; j++) v[j] = make_uint4(0, 0, 0, 0);
        }
        if (TR){
            #pragma unroll
            for (int j = 0; j < 4; j++){
                unsigned* pu = (unsigned*)&v[j];
                #pragma unroll
                for (int c = 0; c < 4; c++){
                    int k = kh * 64 + koU * 2 + j * 8 + c * 2;
                    float f0 = fmaxf(bflo(pu[c]) * sl[k] + tl[k], 0.f);
                    float f1 = fmaxf(bfhi(pu[c]) * sl[k + 1] + tl[k + 1], 0.f);
                    pu[c] = packbf(f0, f1);
                }
            }
        }
        {
            uint4* dst = ((uint4*)As) + r * 8 + (tid & 1) * 4;
            #pragma unroll
            for (int j = 0; j < 4; j++) dst[j] = v[j];
        }
        __syncthreads();
        #pragma unroll
        for (int kc = 0; kc < 2; ++kc){
            int kof = kc * 32 + ((lane >> 4) * 8);
            bf16x8 a0 = ldfrag(&As[(wv * 32 +      (lane & 15)) * 64 + kof]);
            bf16x8 a1 = ldfrag(&As[(wv * 32 + 16 + (lane & 15)) * 64 + kof]);
            int wk = kh * 64 + kof;
            #pragma unroll
            for (int ct = 0; ct < 8; ++ct){
                bf16x8 b = ldfrag(&Wl[(ct * 16 + (lane & 15)) * 128 + wk]);
                acc[0][ct] = __builtin_amdgcn_mfma_f32_16x16x32_bf16(a0, b, acc[0][ct], 0, 0, 0);
                acc[1][ct] = __builtin_amdgcn_mfma_f32_16x16x32_bf16(a1, b, acc[1][ct], 0, 0, 0);
            }
        }
    }
    // epilogue: C/D layout col=lane&15, row=(lane>>4)*4+reg. Store + column stats.
    int cl = lane & 15, rq = lane >> 4;
    float colS[8], colQ[8];
    #pragma unroll
    for (int ct = 0; ct < 8; ++ct){
        float bv = bias[ct * 16 + cl];
        float ps = 0.f, pq = 0.f;
        #pragma unroll
        for (int rt = 0; rt < 2; ++rt){
            #pragma unroll
            for (int rr2 = 0; rr2 < 4; ++rr2){
                int grow = rowbase + wv * 32 + rt * 16 + rq * 4 + rr2;
                if (grow < NN){
                    float val = acc[rt][ct][rr2] + bv;
                    Cst[grow * 128 + ct * 16 + cl] = f2bf(val);
                    ps += val; pq += val * val;
                }
            }
        }
        ps += __shfl_xor(ps, 16); pq += __shfl_xor(pq, 16);
        ps += __shfl_xor(ps, 32); pq += __shfl_xor(pq, 32);
        colS[ct] = ps; colQ[ct] = pq;
    }
    __syncthreads();                       // done with As; reuse as float scratch
    float* sred = (float*)As;              // [0..511]=sums(wv,col), [512..1023]=sumsq
    if (rq == 0){
        #pragma unroll
        for (int ct = 0; ct < 8; ++ct){
            sred[wv * 128 + ct * 16 + cl]       = colS[ct];
            sred[512 + wv * 128 + ct * 16 + cl] = colQ[ct];
        }
    }
    __syncthreads();
    if (tid < 128){
        float s1 = sred[tid] + sred[128 + tid] + sred[256 + tid] + sred[384 + tid];
        float s2 = sred[512 + tid] + sred[640 + tid] + sred[768 + tid] + sred[896 + tid];
        atomicAdd(&ostats[tid], s1);
        atomicAdd(&ostats[128 + tid], s2);
    }
}

// h = relu(bn(z)) (write h) fused with per-graph pooling. One block per graph.
__global__ __launch_bounds__(256) void ewpool_k(const unsigned* __restrict__ z32,
                                                const float* __restrict__ stats,
                                                const float* __restrict__ g,
                                                const float* __restrict__ b,
                                                const int* __restrict__ gstart,
                                                unsigned* __restrict__ h32,
                                                float* __restrict__ outp){
    __shared__ float sd[512];
    int gid = blockIdx.x; int tid = threadIdx.x;
    int c = tid & 63, rs = tid >> 6;
    int c2 = c * 2;
    float m0 = stats[c2] * INV_N,     q0 = stats[128 + c2] * INV_N;
    float inv0 = rsqrtf(q0 - m0 * m0 + BN_EPS);
    float s0 = g[c2] * inv0, t0 = b[c2] - m0 * s0;
    float m1 = stats[c2 + 1] * INV_N, q1 = stats[129 + c2] * INV_N;
    float inv1 = rsqrtf(q1 - m1 * m1 + BN_EPS);
    float s1 = g[c2 + 1] * inv1, t1 = b[c2 + 1] - m1 * s1;
    int s = gstart[gid], e = gstart[gid + 1];
    float a0 = 0.f, a1 = 0.f;
    for (int n = s + rs; n < e; n += 4){
        unsigned u = z32[n * 64 + c];
        float f0 = fmaxf(bflo(u) * s0 + t0, 0.f);
        float f1 = fmaxf(bfhi(u) * s1 + t1, 0.f);
        h32[n * 64 + c] = packbf(f0, f1);
        a0 += f0; a1 += f1;
    }
    sd[tid] = a0; sd[256 + tid] = a1; __syncthreads();
    if (tid < 64){
        float r0 = 0.f, r1 = 0.f;
        #pragma unroll
        for (int k2 = 0; k2 < 4; k2++){ r0 += sd[tid + 64 * k2]; r1 += sd[256 + tid + 64 * k2]; }
        outp[gid * 128 + 2 * tid] = r0; outp[gid * 128 + 2 * tid + 1] = r1;
    }
}

// pooled[0] from fp32 x (exact)
__global__ __launch_bounds__(256) void poolx_k(const float* __restrict__ x,
                                               const int* __restrict__ gstart,
                                               float* __restrict__ outp){
    __shared__ float sd[256];
    int g = blockIdx.x; int tid = threadIdx.x; int c = tid & 127, rs = tid >> 7;
    int s = gstart[g], e = gstart[g + 1];
    float a = 0;
    for (int n = s + rs; n < e; n += 2) a += x[n * 128 + c];
    sd[tid] = a; __syncthreads();
    if (tid < 128) outp[g * 128 + tid] = sd[tid] + sd[tid + 128];
}

// logits = sum_i pooled_i @ fcW_i + fcb_i ; out = log_softmax(logits)
__global__ __launch_bounds__(64) void final_k(const float* __restrict__ pooled,
                                              const float* __restrict__ fcW,
                                              const float* __restrict__ fcb,
                                              float* __restrict__ out){
    int g = blockIdx.x, l = threadIdx.x;
    float p0[5], p1[5];
    #pragma unroll
    for (int i = 0; i < 5; i++){
        p0[i] = pooled[i * GD + g * 128 + l];
        p1[i] = pooled[i * GD + g * 128 + 64 + l];
    }
    float lg[10];
    #pragma unroll
    for (int c2 = 0; c2 < 10; c2++){
        float s = 0;
        #pragma unroll
        for (int i = 0; i < 5; i++){
            s += p0[i] * fcW[(i * 128 + l) * 10 + c2];
            s += p1[i] * fcW[(i * 128 + 64 + l) * 10 + c2];
        }
        #pragma unroll
        for (int off = 32; off >= 1; off >>= 1) s += __shfl_down(s, off);
        lg[c2] = s;
    }
    if (l == 0){
        #pragma unroll
        for (int c2 = 0; c2 < 10; c2++){
            float bs = 0;
            #pragma unroll
            for (int i = 0; i < 5; i++) bs += fcb[i * 10 + c2];
            lg[c2] += bs;
        }
        float mx = lg[0];
        #pragma unroll
        for (int c2 = 1; c2 < 10; c2++) mx = fmaxf(mx, lg[c2]);
        float se = 0;
        #pragma unroll
        for (int c2 = 0; c2 < 10; c2++) se += expf(lg[c2] - mx);
        float lse = mx + logf(se);
        #pragma unroll
        for (int c2 = 0; c2 < 10; c2++) out[g * 10 + c2] = lg[c2] - lse;
    }
}

// ---------------- launch ----------------

extern "C" void kernel_launch(void* const* d_in, const int* in_sizes, int n_in,
                              void* d_out, int out_size, void* d_ws, size_t ws_size,
                              hipStream_t stream){
    (void)in_sizes; (void)n_in; (void)out_size; (void)ws_size;
    const float* x     = (const float*)d_in[0];
    const int*   ei    = (const int*)d_in[1];
    const int*   batch = (const int*)d_in[2];
    const float* cW1   = (const float*)d_in[4];
    const float* cb1   = (const float*)d_in[5];
    const float* cbng  = (const float*)d_in[6];
    const float* cbnb  = (const float*)d_in[7];
    const float* cW2   = (const float*)d_in[8];
    const float* cb2   = (const float*)d_in[9];
    const float* bng   = (const float*)d_in[10];
    const float* bnb   = (const float*)d_in[11];
    const float* fcW   = (const float*)d_in[12];
    const float* fcb   = (const float*)d_in[13];

    char* base = (char*)d_ws;
    size_t off = 0;
    auto alloc = [&](size_t bytes) -> void* {
        void* p = base + off;
        off = (off + bytes + 255) & ~(size_t)255;
        return p;
    };
    unsigned*       hB     = (unsigned*)alloc((size_t)NN * 64 * 4);
    unsigned*       zA     = (unsigned*)alloc((size_t)NN * 64 * 4);
    unsigned*       zB     = (unsigned*)alloc((size_t)NN * 64 * 4);
    unsigned short* Wtall  = (unsigned short*)alloc(8 * 16384 * 2);
    int*            ssort  = (int*)alloc((size_t)EE * 4);
    int*            rp4    = (int*)alloc(((size_t)NN * 4 + 1) * 4);
    int*            gstart = (int*)alloc((GG + 1) * 4);
    int*            bucketCnt  = (int*)alloc(NB * 4);
    int*            bucketBase = (int*)alloc((NB + 1) * 4);
    int*            bucketCur  = (int*)alloc(NB * 4);
    float*          pooled = (float*)alloc((size_t)5 * GD * 4);
    float*          stats1 = (float*)alloc(256 * 4);
    float*          stats2 = (float*)alloc(256 * 4);
    unsigned*       binned = (unsigned*)zB;   // alias: binned only used before layer loop

    zero_k<<<1, 256, 0, stream>>>(bucketCnt, NB);
    convx_k<<<NN * 64 / 256, 256, 0, stream>>>((const float2*)x, hB);
    wprep_k<<<512, 256, 0, stream>>>(cW1, cW2, Wtall);
    bhist_k<<<(EE + BK_EDGES - 1) / BK_EDGES, 256, 0, stream>>>(ei + EE, bucketCnt);
    bscan_k<<<1, 256, 0, stream>>>(bucketCnt, bucketBase, bucketCur, rp4);
    gsearch_k<<<3, 256, 0, stream>>>(batch, gstart);
    binA_k<<<(EE + BK_EDGES - 1) / BK_EDGES, 256, 0, stream>>>(ei, ei + EE, bucketCur, binned);
    binB_k<<<NB, 256, 0, stream>>>(binned, bucketBase, rp4, ssort);
    poolx_k<<<GG, 256, 0, stream>>>(x, gstart, pooled);

    const int gemmGrid = (NN + 127) / 128;
    for (int i = 0; i < LLAY; i++){
        agg_k<<<NN / 4, 256, 0, stream>>>(hB, rp4, ssort, zA, stats1);
        gemm_k<0><<<gemmGrid, 256, 0, stream>>>(zA, Wtall + i * 16384, cb1 + i * 128,
                                                (unsigned short*)zB,
                                                nullptr, nullptr, nullptr, stats1, stats2);
        gemm_k<1><<<gemmGrid, 256, 0, stream>>>(zB, Wtall + (4 + i) * 16384, cb2 + i * 128,
                                                (unsigned short*)zA,
                                                stats1, cbng + i * 128, cbnb + i * 128, stats2, nullptr);
        ewpool_k<<<GG, 256, 0, stream>>>(zA, stats2, bng + i * 128, bnb + i * 128,
                                         gstart, hB, pooled + (size_t)(i + 1) * GD);
    }
    final_k<<<GG, 64, 0, stream>>>(pooled, fcW, fcb, (float*)d_out);
}

// Round 7
// 598.299 us; speedup vs baseline: 1.3113x; 1.0688x over previous
//
#include <hip/hip_runtime.h>

#define NN 50000
#define EE 1600000
#define DD 128
#define CC 10
#define LLAY 4
#define GG 512
#define GD (GG*DD)
#define NB 196           // ceil(NN/256) coarse buckets
#define BK_EDGES 6400    // edges per binA/bhist block
#define NSUB 16          // src sub-tiles per node list (0.78MB each -> L2-resident window)
#define SUBW 3125        // 50000/16

static constexpr float BN_EPS = 1e-5f;
static constexpr float INV_N = 1.0f / (float)NN;

typedef __bf16 bf16x8 __attribute__((ext_vector_type(8)));
typedef float f32x4 __attribute__((ext_vector_type(4)));

static __device__ __forceinline__ float bflo(unsigned u){ return __uint_as_float(u << 16); }
static __device__ __forceinline__ float bfhi(unsigned u){ return __uint_as_float(u & 0xffff0000u); }
static __device__ __forceinline__ unsigned short f2bf(float f){
    unsigned u = __float_as_uint(f);
    return (unsigned short)((u + 0x7fffu + ((u >> 16) & 1u)) >> 16);   // RNE
}
static __device__ __forceinline__ unsigned packbf(float a, float b){
    return (unsigned)f2bf(a) | ((unsigned)f2bf(b) << 16);
}
static __device__ __forceinline__ bf16x8 ldfrag(const unsigned short* p){
    union { uint4 u; bf16x8 b; } t; t.u = *(const uint4*)p; return t.b;
}
static __device__ __forceinline__ bf16x8 asfrag(uint4 u){
    union { uint4 u; bf16x8 b; } t; t.u = u; return t.b;
}

// ---------------- setup kernels ----------------

__global__ void zero_k(int* p, int n){
    int i = blockIdx.x * 256 + threadIdx.x;
    if (i < n) p[i] = 0;
}

// x (fp32) -> [n][64] packed bf16-pair layout
__global__ void convx_k(const float2* __restrict__ x2, unsigned* __restrict__ h32){
    int i = blockIdx.x * 256 + threadIdx.x;   // grid covers NN*64 exactly
    float2 v = x2[i];
    h32[i] = packbf(v.x, v.y);
}

// all 8 weight matrices -> bf16 W^T [j][k] in ws
__global__ void wprep_k(const float* __restrict__ W1, const float* __restrict__ W2,
                        unsigned short* __restrict__ Wtall){
    int idx = blockIdx.x * 256 + threadIdx.x;         // < 8*16384
    int mat = idx >> 14; int rr = idx & 16383;
    int k = rr >> 7; int j = rr & 127;
    const float* Wsrc = (mat < 4) ? (W1 + mat * 16384) : (W2 + (mat - 4) * 16384);
    Wtall[mat * 16384 + j * 128 + k] = f2bf(Wsrc[k * 128 + j]);
}

// bucket-level histogram (196 buckets of 256 dst nodes)
__global__ __launch_bounds__(256) void bhist_k(const int* __restrict__ dstA,
                                               int* __restrict__ bucketCnt){
    __shared__ int c[NB];
    int tid = threadIdx.x;
    if (tid < NB) c[tid] = 0;
    __syncthreads();
    int e0 = blockIdx.x * BK_EDGES;
    for (int i = tid; i < BK_EDGES; i += 256){
        int e = e0 + i;
        if (e < EE) atomicAdd(&c[dstA[e] >> 8], 1);
    }
    __syncthreads();
    if (tid < NB && c[tid] > 0) atomicAdd(&bucketCnt[tid], c[tid]);
}

// scan bucket counts -> bucketBase / bucketCur; terminal rp entry
__global__ __launch_bounds__(256) void bscan_k(const int* __restrict__ bucketCnt,
                                               int* __restrict__ bucketBase,
                                               int* __restrict__ bucketCur,
                                               int* __restrict__ rp){
    __shared__ int lds[256];
    int t = threadIdx.x;
    int v = (t < NB) ? bucketCnt[t] : 0;
    lds[t] = v; __syncthreads();
    for (int o = 1; o < 256; o <<= 1){
        int xv = 0; if (t >= o) xv = lds[t - o];
        __syncthreads(); lds[t] += xv; __syncthreads();
    }
    int excl = lds[t] - v;
    if (t < NB){ bucketBase[t] = excl; bucketCur[t] = excl; }
    if (t == 0){ bucketBase[NB] = EE; rp[NN] = EE; }
}

// graph boundaries via binary search on sorted batch
__global__ void gsearch_k(const int* __restrict__ batch, int* __restrict__ gstart){
    int g = blockIdx.x * 256 + threadIdx.x;
    if (g <= GG){
        int lo = 0, hi = NN;
        while (lo < hi){ int mid = (lo + hi) >> 1; if (batch[mid] < g) lo = mid + 1; else hi = mid; }
        gstart[g] = lo;
    }
}

// Pass A: bin edges into NB coarse buckets, contiguous runs.
__global__ __launch_bounds__(256) void binA_k(const int* __restrict__ srcA,
                                              const int* __restrict__ dstA,
                                              int* __restrict__ bucketCur,
                                              unsigned* __restrict__ binned){
    __shared__ int cnt[NB], bas[NB], off[NB];
    int tid = threadIdx.x;
    if (tid < NB){ cnt[tid] = 0; off[tid] = 0; }
    __syncthreads();
    int e0 = blockIdx.x * BK_EDGES;
    for (int i = tid; i < BK_EDGES; i += 256){
        int e = e0 + i;
        if (e < EE) atomicAdd(&cnt[dstA[e] >> 8], 1);
    }
    __syncthreads();
    if (tid < NB && cnt[tid] > 0) bas[tid] = atomicAdd(&bucketCur[tid], cnt[tid]);
    __syncthreads();
    for (int i = tid; i < BK_EDGES; i += 256){
        int e = e0 + i;
        if (e < EE){
            int d = dstA[e]; int b = d >> 8;
            int p = bas[b] + atomicAdd(&off[b], 1);
            binned[p] = (unsigned)srcA[e] | ((unsigned)(d & 255) << 17);  // src<2^17
        }
    }
}

// Pass B: per-bucket (node, 16-subtile) counts -> rp + src-sorted placement.
__global__ __launch_bounds__(256) void binB_k(const unsigned* __restrict__ binned,
                                              const int* __restrict__ bucketBase,
                                              int* __restrict__ rp,
                                              int* __restrict__ ssort){
    __shared__ int c16[256 * NSUB];   // 16 KB
    __shared__ int b16[256 * NSUB];   // 16 KB
    __shared__ int nt[256];
    int b = blockIdx.x, tid = threadIdx.x;
    int nb0 = b * 256;
    int nmax = NN - nb0; if (nmax > 256) nmax = 256;
    #pragma unroll
    for (int k = 0; k < NSUB; k++) c16[tid * NSUB + k] = 0;
    __syncthreads();
    int base = bucketBase[b];
    int end  = bucketBase[b + 1];
    for (int i = base + tid; i < end; i += 256){
        unsigned u = binned[i];
        int src = (int)(u & 0x1FFFFu); int dl = (int)(u >> 17);
        atomicAdd(&c16[dl * NSUB + src / SUBW], 1);
    }
    __syncthreads();
    int cc[NSUB]; int tot = 0;
    #pragma unroll
    for (int k = 0; k < NSUB; k++){ cc[k] = c16[tid * NSUB + k]; tot += cc[k]; }
    nt[tid] = tot; __syncthreads();
    for (int o = 1; o < 256; o <<= 1){
        int xv = 0; if (tid >= o) xv = nt[tid - o];
        __syncthreads(); nt[tid] += xv; __syncthreads();
    }
    int p = base + nt[tid] - tot;
    if (tid < nmax) rp[nb0 + tid] = p;
    int run = p;
    #pragma unroll
    for (int k = 0; k < NSUB; k++){ b16[tid * NSUB + k] = run; run += cc[k]; }
    #pragma unroll
    for (int k = 0; k < NSUB; k++) c16[tid * NSUB + k] = 0;
    __syncthreads();
    for (int i = base + tid; i < end; i += 256){
        unsigned u = binned[i];
        int src = (int)(u & 0x1FFFFu); int dl = (int)(u >> 17);
        int t = src / SUBW;
        int pos = b16[dl * NSUB + t] + atomicAdd(&c16[dl * NSUB + t], 1);
        ssort[pos] = src;
    }
}

// ---------------- per-layer kernels ----------------

// z = h + sum_{in-edges} h[src]  (edges per node sorted by src -> L2-local window)
__global__ __launch_bounds__(256) void agg_k(const unsigned* __restrict__ h32,
                                             const int* __restrict__ rp,
                                             const int* __restrict__ ssort,
                                             unsigned* __restrict__ z32,
                                             float* __restrict__ zstats){
    int tid = threadIdx.x;
    if (blockIdx.x == 0) zstats[tid] = 0.f;
    int n = blockIdx.x * 4 + (tid >> 6);  // grid*4 == NN exactly
    int lane = tid & 63;
    unsigned self = h32[n * 64 + lane];
    float ax = bflo(self), ay = bfhi(self);
    int e  = __builtin_amdgcn_readfirstlane(rp[n]);
    int e1 = __builtin_amdgcn_readfirstlane(rp[n + 1]);
    for (; e + 7 < e1; e += 8){
        int s0 = ssort[e],     s1 = ssort[e + 1], s2 = ssort[e + 2], s3 = ssort[e + 3];
        int s4 = ssort[e + 4], s5 = ssort[e + 5], s6 = ssort[e + 6], s7 = ssort[e + 7];
        unsigned u0 = h32[s0 * 64 + lane];
        unsigned u1 = h32[s1 * 64 + lane];
        unsigned u2 = h32[s2 * 64 + lane];
        unsigned u3 = h32[s3 * 64 + lane];
        unsigned u4 = h32[s4 * 64 + lane];
        unsigned u5 = h32[s5 * 64 + lane];
        unsigned u6 = h32[s6 * 64 + lane];
        unsigned u7 = h32[s7 * 64 + lane];
        ax += bflo(u0) + bflo(u1); ay += bfhi(u0) + bfhi(u1);
        ax += bflo(u2) + bflo(u3); ay += bfhi(u2) + bfhi(u3);
        ax += bflo(u4) + bflo(u5); ay += bfhi(u4) + bfhi(u5);
        ax += bflo(u6) + bflo(u7); ay += bfhi(u6) + bfhi(u7);
    }
    for (; e < e1; ++e){
        unsigned u0 = h32[ssort[e] * 64 + lane];
        ax += bflo(u0); ay += bfhi(u0);
    }
    z32[n * 64 + lane] = packbf(ax, ay);
}

// C[N,128] = opt_relu_bn(A[N,128]) @ W[128,128] + bias, bf16 MFMA 16x16x32.
// A-frags loaded DIRECTLY from global (no LDS staging, 1 barrier, all loads in flight).
// Fused epilogue: column sum/sumsq of fp32 C -> atomicAdd into ostats.
template<int TR>
__global__ __launch_bounds__(256) void gemm_k(const unsigned* __restrict__ A32,
                                              const unsigned short* __restrict__ Wtg,
                                              const float* __restrict__ bias,
                                              unsigned short* __restrict__ Cst,
                                              const float* __restrict__ stats,
                                              const float* __restrict__ gma,
                                              const float* __restrict__ bta,
                                              float* __restrict__ ostats,
                                              float* __restrict__ zstats){
    __shared__ __align__(16) unsigned short Wl[128 * 128];  // [j][k] 32KB
    __shared__ float sred[1024];                            // 4KB epilogue scratch
    __shared__ __align__(16) float sl[128], tl[128];
    int tid = threadIdx.x;
    if (blockIdx.x == 0 && zstats) zstats[tid] = 0.f;
    {
        const uint4* src = (const uint4*)Wtg; uint4* dst = (uint4*)Wl;
        #pragma unroll
        for (int i = 0; i < 8; i++) dst[tid + 256 * i] = src[tid + 256 * i];
    }
    if (TR && tid < 128){
        float mean = stats[tid] * INV_N;
        float q    = stats[128 + tid] * INV_N;
        float inv  = rsqrtf(q - mean * mean + BN_EPS);
        float s    = gma[tid] * inv;
        sl[tid] = s; tl[tid] = bta[tid] - mean * s;
    }
    __syncthreads();

    int wv = tid >> 6, lane = tid & 63;
    int rowbase = blockIdx.x * 128 + wv * 32;
    int r0 = rowbase + (lane & 15);
    int r1 = r0 + 16;
    int kd = (lane >> 4) * 4;       // dword offset within 16-dword k-group

    uint4 va[4], vb[4];
    #pragma unroll
    for (int ks = 0; ks < 4; ks++){
        va[ks] = (r0 < NN) ? *(const uint4*)(A32 + r0 * 64 + ks * 16 + kd) : make_uint4(0,0,0,0);
        vb[ks] = (r1 < NN) ? *(const uint4*)(A32 + r1 * 64 + ks * 16 + kd) : make_uint4(0,0,0,0);
    }
    if (TR){
        #pragma unroll
        for (int ks = 0; ks < 4; ks++){
            int q = ks * 8 + (lane >> 4) * 2;       // float4 index: k0/4
            float4 sA = ((const float4*)sl)[q], sB = ((const float4*)sl)[q + 1];
            float4 tA = ((const float4*)tl)[q], tB = ((const float4*)tl)[q + 1];
            float fs[8] = {sA.x, sA.y, sA.z, sA.w, sB.x, sB.y, sB.z, sB.w};
            float ft[8] = {tA.x, tA.y, tA.z, tA.w, tB.x, tB.y, tB.z, tB.w};
            unsigned* pa = (unsigned*)&va[ks];
            unsigned* pb = (unsigned*)&vb[ks];
            #pragma unroll
            for (int c = 0; c < 4; c++){
                float f0 = fmaxf(bflo(pa[c]) * fs[2*c] + ft[2*c], 0.f);
                float f1 = fmaxf(bfhi(pa[c]) * fs[2*c+1] + ft[2*c+1], 0.f);
                pa[c] = packbf(f0, f1);
                f0 = fmaxf(bflo(pb[c]) * fs[2*c] + ft[2*c], 0.f);
                f1 = fmaxf(bfhi(pb[c]) * fs[2*c+1] + ft[2*c+1], 0.f);
                pb[c] = packbf(f0, f1);
            }
        }
    }

    f32x4 acc[2][8];
    #pragma unroll
    for (int a = 0; a < 2; a++)
        #pragma unroll
        for (int b = 0; b < 8; b++) acc[a][b] = (f32x4){0.f, 0.f, 0.f, 0.f};

    #pragma unroll
    for (int ks = 0; ks < 4; ks++){
        int wk = ks * 32 + (lane >> 4) * 8;
        bf16x8 a0 = asfrag(va[ks]);
        bf16x8 a1 = asfrag(vb[ks]);
        #pragma unroll
        for (int ct = 0; ct < 8; ++ct){
            bf16x8 b = ldfrag(&Wl[(ct * 16 + (lane & 15)) * 128 + wk]);
            acc[0][ct] = __builtin_amdgcn_mfma_f32_16x16x32_bf16(a0, b, acc[0][ct], 0, 0, 0);
            acc[1][ct] = __builtin_amdgcn_mfma_f32_16x16x32_bf16(a1, b, acc[1][ct], 0, 0, 0);
        }
    }

    // epilogue: C/D layout col=lane&15, row=(lane>>4)*4+reg. Store + column stats.
    int cl = lane & 15, rq = lane >> 4;
    float colS[8], colQ[8];
    #pragma unroll
    for (int ct = 0; ct < 8; ++ct){
        float bv = bias[ct * 16 + cl];
        float ps = 0.f, pq = 0.f;
        #pragma unroll
        for (int rt = 0; rt < 2; ++rt){
            #pragma unroll
            for (int rr2 = 0; rr2 < 4; ++rr2){
                int grow = rowbase + rt * 16 + rq * 4 + rr2;
                if (grow < NN){
                    float val = acc[rt][ct][rr2] + bv;
                    Cst[grow * 128 + ct * 16 + cl] = f2bf(val);
                    ps += val; pq += val * val;
                }
            }
        }
        ps += __shfl_xor(ps, 16); pq += __shfl_xor(pq, 16);
        ps += __shfl_xor(ps, 32); pq += __shfl_xor(pq, 32);
        colS[ct] = ps; colQ[ct] = pq;
    }
    if (rq == 0){
        #pragma unroll
        for (int ct = 0; ct < 8; ++ct){
            sred[wv * 128 + ct * 16 + cl]       = colS[ct];
            sred[512 + wv * 128 + ct * 16 + cl] = colQ[ct];
        }
    }
    __syncthreads();
    if (tid < 128){
        float s1 = sred[tid] + sred[128 + tid] + sred[256 + tid] + sred[384 + tid];
        float s2 = sred[512 + tid] + sred[640 + tid] + sred[768 + tid] + sred[896 + tid];
        atomicAdd(&ostats[tid], s1);
        atomicAdd(&ostats[128 + tid], s2);
    }
}

// h = relu(bn(z)) (write h) fused with per-graph pooling. One block per graph, ILP-4.
__global__ __launch_bounds__(256) void ewpool_k(const unsigned* __restrict__ z32,
                                                const float* __restrict__ stats,
                                                const float* __restrict__ g,
                                                const float* __restrict__ b,
                                                const int* __restrict__ gstart,
                                                unsigned* __restrict__ h32,
                                                float* __restrict__ outp){
    __shared__ float sd[512];
    int gid = blockIdx.x; int tid = threadIdx.x;
    int c = tid & 63, rs = tid >> 6;
    int c2 = c * 2;
    float m0 = stats[c2] * INV_N,     q0 = stats[128 + c2] * INV_N;
    float inv0 = rsqrtf(q0 - m0 * m0 + BN_EPS);
    float s0 = g[c2] * inv0, t0 = b[c2] - m0 * s0;
    float m1 = stats[c2 + 1] * INV_N, q1 = stats[129 + c2] * INV_N;
    float inv1 = rsqrtf(q1 - m1 * m1 + BN_EPS);
    float s1 = g[c2 + 1] * inv1, t1 = b[c2 + 1] - m1 * s1;
    int s = gstart[gid], e = gstart[gid + 1];
    float a0 = 0.f, a1 = 0.f;
    int n = s + rs;
    for (; n + 12 < e; n += 16){
        unsigned u0 = z32[n * 64 + c];
        unsigned u1 = z32[(n + 4) * 64 + c];
        unsigned u2 = z32[(n + 8) * 64 + c];
        unsigned u3 = z32[(n + 12) * 64 + c];
        float f0, f1;
        f0 = fmaxf(bflo(u0) * s0 + t0, 0.f); f1 = fmaxf(bfhi(u0) * s1 + t1, 0.f);
        h32[n * 64 + c] = packbf(f0, f1); a0 += f0; a1 += f1;
        f0 = fmaxf(bflo(u1) * s0 + t0, 0.f); f1 = fmaxf(bfhi(u1) * s1 + t1, 0.f);
        h32[(n + 4) * 64 + c] = packbf(f0, f1); a0 += f0; a1 += f1;
        f0 = fmaxf(bflo(u2) * s0 + t0, 0.f); f1 = fmaxf(bfhi(u2) * s1 + t1, 0.f);
        h32[(n + 8) * 64 + c] = packbf(f0, f1); a0 += f0; a1 += f1;
        f0 = fmaxf(bflo(u3) * s0 + t0, 0.f); f1 = fmaxf(bfhi(u3) * s1 + t1, 0.f);
        h32[(n + 12) * 64 + c] = packbf(f0, f1); a0 += f0; a1 += f1;
    }
    for (; n < e; n += 4){
        unsigned u = z32[n * 64 + c];
        float f0 = fmaxf(bflo(u) * s0 + t0, 0.f);
        float f1 = fmaxf(bfhi(u) * s1 + t1, 0.f);
        h32[n * 64 + c] = packbf(f0, f1);
        a0 += f0; a1 += f1;
    }
    sd[tid] = a0; sd[256 + tid] = a1; __syncthreads();
    if (tid < 64){
        float r0 = 0.f, r1 = 0.f;
        #pragma unroll
        for (int k2 = 0; k2 < 4; k2++){ r0 += sd[tid + 64 * k2]; r1 += sd[256 + tid + 64 * k2]; }
        outp[gid * 128 + 2 * tid] = r0; outp[gid * 128 + 2 * tid + 1] = r1;
    }
}

// pooled[0] from fp32 x (exact), ILP-4
__global__ __launch_bounds__(256) void poolx_k(const float* __restrict__ x,
                                               const int* __restrict__ gstart,
                                               float* __restrict__ outp){
    __shared__ float sd[256];
    int g = blockIdx.x; int tid = threadIdx.x; int c = tid & 127, rs = tid >> 7;
    int s = gstart[g], e = gstart[g + 1];
    float a = 0;
    int n = s + rs;
    for (; n + 6 < e; n += 8){
        float v0 = x[n * 128 + c], v1 = x[(n + 2) * 128 + c];
        float v2 = x[(n + 4) * 128 + c], v3 = x[(n + 6) * 128 + c];
        a += (v0 + v1) + (v2 + v3);
    }
    for (; n < e; n += 2) a += x[n * 128 + c];
    sd[tid] = a; __syncthreads();
    if (tid < 128) outp[g * 128 + tid] = sd[tid] + sd[tid + 128];
}

// logits = sum_i pooled_i @ fcW_i + fcb_i ; out = log_softmax(logits)
__global__ __launch_bounds__(64) void final_k(const float* __restrict__ pooled,
                                              const float* __restrict__ fcW,
                                              const float* __restrict__ fcb,
                                              float* __restrict__ out){
    int g = blockIdx.x, l = threadIdx.x;
    float p0[5], p1[5];
    #pragma unroll
    for (int i = 0; i < 5; i++){
        p0[i] = pooled[i * GD + g * 128 + l];
        p1[i] = pooled[i * GD + g * 128 + 64 + l];
    }
    float lg[10];
    #pragma unroll
    for (int c2 = 0; c2 < 10; c2++){
        float s = 0;
        #pragma unroll
        for (int i = 0; i < 5; i++){
            s += p0[i] * fcW[(i * 128 + l) * 10 + c2];
            s += p1[i] * fcW[(i * 128 + 64 + l) * 10 + c2];
        }
        #pragma unroll
        for (int off = 32; off >= 1; off >>= 1) s += __shfl_down(s, off);
        lg[c2] = s;
    }
    if (l == 0){
        #pragma unroll
        for (int c2 = 0; c2 < 10; c2++){
            float bs = 0;
            #pragma unroll
            for (int i = 0; i < 5; i++) bs += fcb[i * 10 + c2];
            lg[c2] += bs;
        }
        float mx = lg[0];
        #pragma unroll
        for (int c2 = 1; c2 < 10; c2++) mx = fmaxf(mx, lg[c2]);
        float se = 0;
        #pragma unroll
        for (int c2 = 0; c2 < 10; c2++) se += expf(lg[c2] - mx);
        float lse = mx + logf(se);
        #pragma unroll
        for (int c2 = 0; c2 < 10; c2++) out[g * 10 + c2] = lg[c2] - lse;
    }
}

// ---------------- launch ----------------

extern "C" void kernel_launch(void* const* d_in, const int* in_sizes, int n_in,
                              void* d_out, int out_size, void* d_ws, size_t ws_size,
                              hipStream_t stream){
    (void)in_sizes; (void)n_in; (void)out_size; (void)ws_size;
    const float* x     = (const float*)d_in[0];
    const int*   ei    = (const int*)d_in[1];
    const int*   batch = (const int*)d_in[2];
    const float* cW1   = (const float*)d_in[4];
    const float* cb1   = (const float*)d_in[5];
    const float* cbng  = (const float*)d_in[6];
    const float* cbnb  = (const float*)d_in[7];
    const float* cW2   = (const float*)d_in[8];
    const float* cb2   = (const float*)d_in[9];
    const float* bng   = (const float*)d_in[10];
    const float* bnb   = (const float*)d_in[11];
    const float* fcW   = (const float*)d_in[12];
    const float* fcb   = (const float*)d_in[13];

    char* base = (char*)d_ws;
    size_t off = 0;
    auto alloc = [&](size_t bytes) -> void* {
        void* p = base + off;
        off = (off + bytes + 255) & ~(size_t)255;
        return p;
    };
    unsigned*       hB     = (unsigned*)alloc((size_t)NN * 64 * 4);
    unsigned*       zA     = (unsigned*)alloc((size_t)NN * 64 * 4);
    unsigned*       zB     = (unsigned*)alloc((size_t)NN * 64 * 4);
    unsigned short* Wtall  = (unsigned short*)alloc(8 * 16384 * 2);
    int*            ssort  = (int*)alloc((size_t)EE * 4);
    int*            rp     = (int*)alloc((NN + 1) * 4);
    int*            gstart = (int*)alloc((GG + 1) * 4);
    int*            bucketCnt  = (int*)alloc(NB * 4);
    int*            bucketBase = (int*)alloc((NB + 1) * 4);
    int*            bucketCur  = (int*)alloc(NB * 4);
    float*          pooled = (float*)alloc((size_t)5 * GD * 4);
    float*          stats1 = (float*)alloc(256 * 4);
    float*          stats2 = (float*)alloc(256 * 4);
    unsigned*       binned = (unsigned*)zB;   // alias: binned only used before layer loop

    zero_k<<<1, 256, 0, stream>>>(bucketCnt, NB);
    convx_k<<<NN * 64 / 256, 256, 0, stream>>>((const float2*)x, hB);
    wprep_k<<<512, 256, 0, stream>>>(cW1, cW2, Wtall);
    bhist_k<<<(EE + BK_EDGES - 1) / BK_EDGES, 256, 0, stream>>>(ei + EE, bucketCnt);
    bscan_k<<<1, 256, 0, stream>>>(bucketCnt, bucketBase, bucketCur, rp);
    gsearch_k<<<3, 256, 0, stream>>>(batch, gstart);
    binA_k<<<(EE + BK_EDGES - 1) / BK_EDGES, 256, 0, stream>>>(ei, ei + EE, bucketCur, binned);
    binB_k<<<NB, 256, 0, stream>>>(binned, bucketBase, rp, ssort);
    poolx_k<<<GG, 256, 0, stream>>>(x, gstart, pooled);

    const int gemmGrid = (NN + 127) / 128;
    for (int i = 0; i < LLAY; i++){
        agg_k<<<NN / 4, 256, 0, stream>>>(hB, rp, ssort, zA, stats1);
        gemm_k<0><<<gemmGrid, 256, 0, stream>>>(zA, Wtall + i * 16384, cb1 + i * 128,
                                                (unsigned short*)zB,
                                                nullptr, nullptr, nullptr, stats1, stats2);
        gemm_k<1><<<gemmGrid, 256, 0, stream>>>(zB, Wtall + (4 + i) * 16384, cb2 + i * 128,
                                                (unsigned short*)zA,
                                                stats1, cbng + i * 128, cbnb + i * 128, stats2, nullptr);
        ewpool_k<<<GG, 256, 0, stream>>>(zA, stats2, bng + i * 128, bnb + i * 128,
                                         gstart, hB, pooled + (size_t)(i + 1) * GD);
    }
    final_k<<<GG, 64, 0, stream>>>(pooled, fcW, fcb, (float*)d_out);
}

// Round 9
// 571.225 us; speedup vs baseline: 1.3735x; 1.0474x over previous
//
#include <hip/hip_runtime.h>

#define NN 50000
#define EE 1600000
#define DD 128
#define CC 10
#define LLAY 4
#define GG 512
#define GD (GG*DD)
#define NB 196           // ceil(NN/256) coarse buckets
#define BK_EDGES 6400    // edges per binA/bhist block
#define NSUB 16          // src sub-tiles per node list (sorted gather window)
#define SUBW 3125        // 50000/16
#define WPAD 136         // Wl row stride in shorts (272B = 17 uint4: 2-way banks = free)

static constexpr float BN_EPS = 1e-5f;
static constexpr float INV_N = 1.0f / (float)NN;

typedef __bf16 bf16x8 __attribute__((ext_vector_type(8)));
typedef float f32x4 __attribute__((ext_vector_type(4)));

static __device__ __forceinline__ float bflo(unsigned u){ return __uint_as_float(u << 16); }
static __device__ __forceinline__ float bfhi(unsigned u){ return __uint_as_float(u & 0xffff0000u); }
static __device__ __forceinline__ unsigned short f2bf(float f){
    unsigned u = __float_as_uint(f);
    return (unsigned short)((u + 0x7fffu + ((u >> 16) & 1u)) >> 16);   // RNE
}
static __device__ __forceinline__ unsigned packbf(float a, float b){
    return (unsigned)f2bf(a) | ((unsigned)f2bf(b) << 16);
}
static __device__ __forceinline__ bf16x8 ldfrag(const unsigned short* p){
    union { uint4 u; bf16x8 b; } t; t.u = *(const uint4*)p; return t.b;
}
static __device__ __forceinline__ bf16x8 asfrag(uint4 u){
    union { uint4 u; bf16x8 b; } t; t.u = u; return t.b;
}

// ---------------- setup kernels ----------------

__global__ void zero_k(int* p, int n){
    int i = blockIdx.x * 256 + threadIdx.x;
    if (i < n) p[i] = 0;
}

// x (fp32) -> [n][64] packed bf16-pair layout
__global__ void convx_k(const float2* __restrict__ x2, unsigned* __restrict__ h32){
    int i = blockIdx.x * 256 + threadIdx.x;   // grid covers NN*64 exactly
    float2 v = x2[i];
    h32[i] = packbf(v.x, v.y);
}

// all 8 weight matrices -> bf16 W^T [j][k] in ws
__global__ void wprep_k(const float* __restrict__ W1, const float* __restrict__ W2,
                        unsigned short* __restrict__ Wtall){
    int idx = blockIdx.x * 256 + threadIdx.x;         // < 8*16384
    int mat = idx >> 14; int rr = idx & 16383;
    int k = rr >> 7; int j = rr & 127;
    const float* Wsrc = (mat < 4) ? (W1 + mat * 16384) : (W2 + (mat - 4) * 16384);
    Wtall[mat * 16384 + j * 128 + k] = f2bf(Wsrc[k * 128 + j]);
}

// bucket-level histogram (196 buckets of 256 dst nodes)
__global__ __launch_bounds__(256) void bhist_k(const int* __restrict__ dstA,
                                               int* __restrict__ bucketCnt){
    __shared__ int c[NB];
    int tid = threadIdx.x;
    if (tid < NB) c[tid] = 0;
    __syncthreads();
    int e0 = blockIdx.x * BK_EDGES;
    for (int i = tid; i < BK_EDGES; i += 256){
        int e = e0 + i;
        if (e < EE) atomicAdd(&c[dstA[e] >> 8], 1);
    }
    __syncthreads();
    if (tid < NB && c[tid] > 0) atomicAdd(&bucketCnt[tid], c[tid]);
}

// scan bucket counts -> bucketBase / bucketCur; terminal rp entry
__global__ __launch_bounds__(256) void bscan_k(const int* __restrict__ bucketCnt,
                                               int* __restrict__ bucketBase,
                                               int* __restrict__ bucketCur,
                                               int* __restrict__ rp){
    __shared__ int lds[256];
    int t = threadIdx.x;
    int v = (t < NB) ? bucketCnt[t] : 0;
    lds[t] = v; __syncthreads();
    for (int o = 1; o < 256; o <<= 1){
        int xv = 0; if (t >= o) xv = lds[t - o];
        __syncthreads(); lds[t] += xv; __syncthreads();
    }
    int excl = lds[t] - v;
    if (t < NB){ bucketBase[t] = excl; bucketCur[t] = excl; }
    if (t == 0){ bucketBase[NB] = EE; rp[NN] = EE; }
}

// graph boundaries via binary search on sorted batch
__global__ void gsearch_k(const int* __restrict__ batch, int* __restrict__ gstart){
    int g = blockIdx.x * 256 + threadIdx.x;
    if (g <= GG){
        int lo = 0, hi = NN;
        while (lo < hi){ int mid = (lo + hi) >> 1; if (batch[mid] < g) lo = mid + 1; else hi = mid; }
        gstart[g] = lo;
    }
}

// Pass A: bin edges into NB coarse buckets, contiguous runs.
__global__ __launch_bounds__(256) void binA_k(const int* __restrict__ srcA,
                                              const int* __restrict__ dstA,
                                              int* __restrict__ bucketCur,
                                              unsigned* __restrict__ binned){
    __shared__ int cnt[NB], bas[NB], off[NB];
    int tid = threadIdx.x;
    if (tid < NB){ cnt[tid] = 0; off[tid] = 0; }
    __syncthreads();
    int e0 = blockIdx.x * BK_EDGES;
    for (int i = tid; i < BK_EDGES; i += 256){
        int e = e0 + i;
        if (e < EE) atomicAdd(&cnt[dstA[e] >> 8], 1);
    }
    __syncthreads();
    if (tid < NB && cnt[tid] > 0) bas[tid] = atomicAdd(&bucketCur[tid], cnt[tid]);
    __syncthreads();
    for (int i = tid; i < BK_EDGES; i += 256){
        int e = e0 + i;
        if (e < EE){
            int d = dstA[e]; int b = d >> 8;
            int p = bas[b] + atomicAdd(&off[b], 1);
            binned[p] = (unsigned)srcA[e] | ((unsigned)(d & 255) << 17);  // src<2^17
        }
    }
}

// Pass B: per-bucket (node, 16-subtile) counts -> rp + src-sorted placement.
__global__ __launch_bounds__(256) void binB_k(const unsigned* __restrict__ binned,
                                              const int* __restrict__ bucketBase,
                                              int* __restrict__ rp,
                                              int* __restrict__ ssort){
    __shared__ int c16[256 * NSUB];   // 16 KB
    __shared__ int b16[256 * NSUB];   // 16 KB
    __shared__ int nt[256];
    int b = blockIdx.x, tid = threadIdx.x;
    int nb0 = b * 256;
    int nmax = NN - nb0; if (nmax > 256) nmax = 256;
    #pragma unroll
    for (int k = 0; k < NSUB; k++) c16[tid * NSUB + k] = 0;
    __syncthreads();
    int base = bucketBase[b];
    int end  = bucketBase[b + 1];
    for (int i = base + tid; i < end; i += 256){
        unsigned u = binned[i];
        int src = (int)(u & 0x1FFFFu); int dl = (int)(u >> 17);
        atomicAdd(&c16[dl * NSUB + src / SUBW], 1);
    }
    __syncthreads();
    int cc[NSUB]; int tot = 0;
    #pragma unroll
    for (int k = 0; k < NSUB; k++){ cc[k] = c16[tid * NSUB + k]; tot += cc[k]; }
    nt[tid] = tot; __syncthreads();
    for (int o = 1; o < 256; o <<= 1){
        int xv = 0; if (tid >= o) xv = nt[tid - o];
        __syncthreads(); nt[tid] += xv; __syncthreads();
    }
    int p = base + nt[tid] - tot;
    if (tid < nmax) rp[nb0 + tid] = p;
    int run = p;
    #pragma unroll
    for (int k = 0; k < NSUB; k++){ b16[tid * NSUB + k] = run; run += cc[k]; }
    #pragma unroll
    for (int k = 0; k < NSUB; k++) c16[tid * NSUB + k] = 0;
    __syncthreads();
    for (int i = base + tid; i < end; i += 256){
        unsigned u = binned[i];
        int src = (int)(u & 0x1FFFFu); int dl = (int)(u >> 17);
        int t = src / SUBW;
        int pos = b16[dl * NSUB + t] + atomicAdd(&c16[dl * NSUB + t], 1);
        ssort[pos] = src;
    }
}

// ---------------- per-layer kernels ----------------

// z = h + sum_{in-edges} h[src]  (edges per node sorted by src -> L2-local window)
__global__ __launch_bounds__(256) void agg_k(const unsigned* __restrict__ h32,
                                             const int* __restrict__ rp,
                                             const int* __restrict__ ssort,
                                             unsigned* __restrict__ z32,
                                             float* __restrict__ zstats){
    int tid = threadIdx.x;
    if (blockIdx.x == 0) zstats[tid] = 0.f;
    int n = blockIdx.x * 4 + (tid >> 6);  // grid*4 == NN exactly
    int lane = tid & 63;
    unsigned self = h32[n * 64 + lane];
    float ax = bflo(self), ay = bfhi(self);
    int e  = __builtin_amdgcn_readfirstlane(rp[n]);
    int e1 = __builtin_amdgcn_readfirstlane(rp[n + 1]);
    for (; e + 7 < e1; e += 8){
        int s0 = ssort[e],     s1 = ssort[e + 1], s2 = ssort[e + 2], s3 = ssort[e + 3];
        int s4 = ssort[e + 4], s5 = ssort[e + 5], s6 = ssort[e + 6], s7 = ssort[e + 7];
        unsigned u0 = h32[s0 * 64 + lane];
        unsigned u1 = h32[s1 * 64 + lane];
        unsigned u2 = h32[s2 * 64 + lane];
        unsigned u3 = h32[s3 * 64 + lane];
        unsigned u4 = h32[s4 * 64 + lane];
        unsigned u5 = h32[s5 * 64 + lane];
        unsigned u6 = h32[s6 * 64 + lane];
        unsigned u7 = h32[s7 * 64 + lane];
        ax += bflo(u0) + bflo(u1); ay += bfhi(u0) + bfhi(u1);
        ax += bflo(u2) + bflo(u3); ay += bfhi(u2) + bfhi(u3);
        ax += bflo(u4) + bflo(u5); ay += bfhi(u4) + bfhi(u5);
        ax += bflo(u6) + bflo(u7); ay += bfhi(u6) + bfhi(u7);
    }
    for (; e < e1; ++e){
        unsigned u0 = h32[ssort[e] * 64 + lane];
        ax += bflo(u0); ay += bfhi(u0);
    }
    z32[n * 64 + lane] = packbf(ax, ay);
}

// C[N, 64-col slice] = opt_relu_bn(A[N,128]) @ W-slice + bias, bf16 MFMA 16x16x32.
// blockIdx = tile*2 + slice. A-frags direct from global; Wl padded (WPAD) -> no bank conflicts.
// Fused epilogue: column sum/sumsq -> atomicAdd into ostats.
template<int TR>
__global__ __launch_bounds__(256) void gemm_k(const unsigned* __restrict__ A32,
                                              const unsigned short* __restrict__ Wtg,
                                              const float* __restrict__ bias,
                                              unsigned short* __restrict__ Cst,
                                              const float* __restrict__ stats,
                                              const float* __restrict__ gma,
                                              const float* __restrict__ bta,
                                              float* __restrict__ ostats,
                                              float* __restrict__ zstats){
    __shared__ __align__(16) unsigned short Wl[64 * WPAD];  // 17.4KB, [j][k] padded
    __shared__ float sred[512];
    __shared__ __align__(16) float sl[128], tl[128];
    int tid = threadIdx.x;
    int slice = blockIdx.x & 1;
    int tileb = blockIdx.x >> 1;
    if (blockIdx.x == 0 && zstats) zstats[tid] = 0.f;
    {   // stage 64 W^T rows [slice*64, slice*64+64): each row = 16 uint4, padded to 17
        const uint4* src = (const uint4*)(Wtg + slice * 64 * 128);
        uint4* dst = (uint4*)Wl;
        #pragma unroll
        for (int i = 0; i < 4; i++){
            int idx = tid + 256 * i;            // 0..1023
            int row = idx >> 4, c16 = idx & 15; // 64 rows x 16 uint4
            dst[row * (WPAD / 8) + c16] = src[idx];   // WPAD/8 = 17 uint4 row stride
        }
    }
    if (TR && tid < 128){
        float mean = stats[tid] * INV_N;
        float q    = stats[128 + tid] * INV_N;
        float inv  = rsqrtf(q - mean * mean + BN_EPS);
        float s    = gma[tid] * inv;
        sl[tid] = s; tl[tid] = bta[tid] - mean * s;
    }
    __syncthreads();

    int wv = tid >> 6, lane = tid & 63;
    int rowbase = tileb * 128 + wv * 32;
    int r0 = rowbase + (lane & 15);
    int r1 = r0 + 16;
    int kd = (lane >> 4) * 4;       // dword offset within 16-dword k-group

    uint4 va[4], vb[4];
    #pragma unroll
    for (int ks = 0; ks < 4; ks++){
        va[ks] = (r0 < NN) ? *(const uint4*)(A32 + r0 * 64 + ks * 16 + kd) : make_uint4(0,0,0,0);
        vb[ks] = (r1 < NN) ? *(const uint4*)(A32 + r1 * 64 + ks * 16 + kd) : make_uint4(0,0,0,0);
    }
    if (TR){
        #pragma unroll
        for (int ks = 0; ks < 4; ks++){
            int q = ks * 8 + (lane >> 4) * 2;       // float4 index: k0/4
            float4 sA = ((const float4*)sl)[q], sB = ((const float4*)sl)[q + 1];
            float4 tA = ((const float4*)tl)[q], tB = ((const float4*)tl)[q + 1];
            float fs[8] = {sA.x, sA.y, sA.z, sA.w, sB.x, sB.y, sB.z, sB.w};
            float ft[8] = {tA.x, tA.y, tA.z, tA.w, tB.x, tB.y, tB.z, tB.w};
            unsigned* pa = (unsigned*)&va[ks];
            unsigned* pb = (unsigned*)&vb[ks];
            #pragma unroll
            for (int c = 0; c < 4; c++){
                float f0 = fmaxf(bflo(pa[c]) * fs[2*c] + ft[2*c], 0.f);
                float f1 = fmaxf(bfhi(pa[c]) * fs[2*c+1] + ft[2*c+1], 0.f);
                pa[c] = packbf(f0, f1);
                f0 = fmaxf(bflo(pb[c]) * fs[2*c] + ft[2*c], 0.f);
                f1 = fmaxf(bfhi(pb[c]) * fs[2*c+1] + ft[2*c+1], 0.f);
                pb[c] = packbf(f0, f1);
            }
        }
    }

    f32x4 acc[2][4];
    #pragma unroll
    for (int a = 0; a < 2; a++)
        #pragma unroll
        for (int b = 0; b < 4; b++) acc[a][b] = (f32x4){0.f, 0.f, 0.f, 0.f};

    #pragma unroll
    for (int ks = 0; ks < 4; ks++){
        int wk = ks * 32 + (lane >> 4) * 8;
        bf16x8 a0 = asfrag(va[ks]);
        bf16x8 a1 = asfrag(vb[ks]);
        #pragma unroll
        for (int ct = 0; ct < 4; ++ct){
            bf16x8 b = ldfrag(&Wl[(ct * 16 + (lane & 15)) * WPAD + wk]);
            acc[0][ct] = __builtin_amdgcn_mfma_f32_16x16x32_bf16(a0, b, acc[0][ct], 0, 0, 0);
            acc[1][ct] = __builtin_amdgcn_mfma_f32_16x16x32_bf16(a1, b, acc[1][ct], 0, 0, 0);
        }
    }

    // epilogue: C/D layout col=lane&15, row=(lane>>4)*4+reg. Store + column stats.
    int cl = lane & 15, rq = lane >> 4;
    float colS[4], colQ[4];
    #pragma unroll
    for (int ct = 0; ct < 4; ++ct){
        int col = slice * 64 + ct * 16 + cl;
        float bv = bias[col];
        float ps = 0.f, pq = 0.f;
        #pragma unroll
        for (int rt = 0; rt < 2; ++rt){
            #pragma unroll
            for (int rr2 = 0; rr2 < 4; ++rr2){
                int grow = rowbase + rt * 16 + rq * 4 + rr2;
                if (grow < NN){
                    float val = acc[rt][ct][rr2] + bv;
                    Cst[grow * 128 + col] = f2bf(val);
                    ps += val; pq += val * val;
                }
            }
        }
        ps += __shfl_xor(ps, 16); pq += __shfl_xor(pq, 16);
        ps += __shfl_xor(ps, 32); pq += __shfl_xor(pq, 32);
        colS[ct] = ps; colQ[ct] = pq;
    }
    if (rq == 0){
        #pragma unroll
        for (int ct = 0; ct < 4; ++ct){
            sred[wv * 64 + ct * 16 + cl]       = colS[ct];
            sred[256 + wv * 64 + ct * 16 + cl] = colQ[ct];
        }
    }
    __syncthreads();
    if (tid < 64){
        float s1 = sred[tid] + sred[64 + tid] + sred[128 + tid] + sred[192 + tid];
        float s2 = sred[256 + tid] + sred[320 + tid] + sred[384 + tid] + sred[448 + tid];
        atomicAdd(&ostats[slice * 64 + tid], s1);
        atomicAdd(&ostats[128 + slice * 64 + tid], s2);
    }
}

// h = relu(bn(z)) (write h) fused with per-graph pooling. One block per graph, ILP-4.
__global__ __launch_bounds__(256) void ewpool_k(const unsigned* __restrict__ z32,
                                                const float* __restrict__ stats,
                                                const float* __restrict__ g,
                                                const float* __restrict__ b,
                                                const int* __restrict__ gstart,
                                                unsigned* __restrict__ h32,
                                                float* __restrict__ outp){
    __shared__ float sd[512];
    int gid = blockIdx.x; int tid = threadIdx.x;
    int c = tid & 63, rs = tid >> 6;
    int c2 = c * 2;
    float m0 = stats[c2] * INV_N,     q0 = stats[128 + c2] * INV_N;
    float inv0 = rsqrtf(q0 - m0 * m0 + BN_EPS);
    float s0 = g[c2] * inv0, t0 = b[c2] - m0 * s0;
    float m1 = stats[c2 + 1] * INV_N, q1 = stats[129 + c2] * INV_N;
    float inv1 = rsqrtf(q1 - m1 * m1 + BN_EPS);
    float s1 = g[c2 + 1] * inv1, t1 = b[c2 + 1] - m1 * s1;
    int s = gstart[gid], e = gstart[gid + 1];
    float a0 = 0.f, a1 = 0.f;
    int n = s + rs;
    for (; n + 12 < e; n += 16){
        unsigned u0 = z32[n * 64 + c];
        unsigned u1 = z32[(n + 4) * 64 + c];
        unsigned u2 = z32[(n + 8) * 64 + c];
        unsigned u3 = z32[(n + 12) * 64 + c];
        float f0, f1;
        f0 = fmaxf(bflo(u0) * s0 + t0, 0.f); f1 = fmaxf(bfhi(u0) * s1 + t1, 0.f);
        h32[n * 64 + c] = packbf(f0, f1); a0 += f0; a1 += f1;
        f0 = fmaxf(bflo(u1) * s0 + t0, 0.f); f1 = fmaxf(bfhi(u1) * s1 + t1, 0.f);
        h32[(n + 4) * 64 + c] = packbf(f0, f1); a0 += f0; a1 += f1;
        f0 = fmaxf(bflo(u2) * s0 + t0, 0.f); f1 = fmaxf(bfhi(u2) * s1 + t1, 0.f);
        h32[(n + 8) * 64 + c] = packbf(f0, f1); a0 += f0; a1 += f1;
        f0 = fmaxf(bflo(u3) * s0 + t0, 0.f); f1 = fmaxf(bfhi(u3) * s1 + t1, 0.f);
        h32[(n + 12) * 64 + c] = packbf(f0, f1); a0 += f0; a1 += f1;
    }
    for (; n < e; n += 4){
        unsigned u = z32[n * 64 + c];
        float f0 = fmaxf(bflo(u) * s0 + t0, 0.f);
        float f1 = fmaxf(bfhi(u) * s1 + t1, 0.f);
        h32[n * 64 + c] = packbf(f0, f1);
        a0 += f0; a1 += f1;
    }
    sd[tid] = a0; sd[256 + tid] = a1; __syncthreads();
    if (tid < 64){
        float r0 = 0.f, r1 = 0.f;
        #pragma unroll
        for (int k2 = 0; k2 < 4; k2++){ r0 += sd[tid + 64 * k2]; r1 += sd[256 + tid + 64 * k2]; }
        outp[gid * 128 + 2 * tid] = r0; outp[gid * 128 + 2 * tid + 1] = r1;
    }
}

// pooled[0] from fp32 x (exact), ILP-4
__global__ __launch_bounds__(256) void poolx_k(const float* __restrict__ x,
                                               const int* __restrict__ gstart,
                                               float* __restrict__ outp){
    __shared__ float sd[256];
    int g = blockIdx.x; int tid = threadIdx.x; int c = tid & 127, rs = tid >> 7;
    int s = gstart[g], e = gstart[g + 1];
    float a = 0;
    int n = s + rs;
    for (; n + 6 < e; n += 8){
        float v0 = x[n * 128 + c], v1 = x[(n + 2) * 128 + c];
        float v2 = x[(n + 4) * 128 + c], v3 = x[(n + 6) * 128 + c];
        a += (v0 + v1) + (v2 + v3);
    }
    for (; n < e; n += 2) a += x[n * 128 + c];
    sd[tid] = a; __syncthreads();
    if (tid < 128) outp[g * 128 + tid] = sd[tid] + sd[tid + 128];
}

// logits = sum_i pooled_i @ fcW_i + fcb_i ; out = log_softmax(logits)
__global__ __launch_bounds__(64) void final_k(const float* __restrict__ pooled,
                                              const float* __restrict__ fcW,
                                              const float* __restrict__ fcb,
                                              float* __restrict__ out){
    int g = blockIdx.x, l = threadIdx.x;
    float p0[5], p1[5];
    #pragma unroll
    for (int i = 0; i < 5; i++){
        p0[i] = pooled[i * GD + g * 128 + l];
        p1[i] = pooled[i * GD + g * 128 + 64 + l];
    }
    float lg[10];
    #pragma unroll
    for (int c2 = 0; c2 < 10; c2++){
        float s = 0;
        #pragma unroll
        for (int i = 0; i < 5; i++){
            s += p0[i] * fcW[(i * 128 + l) * 10 + c2];
            s += p1[i] * fcW[(i * 128 + 64 + l) * 10 + c2];
        }
        #pragma unroll
        for (int off = 32; off >= 1; off >>= 1) s += __shfl_down(s, off);
        lg[c2] = s;
    }
    if (l == 0){
        #pragma unroll
        for (int c2 = 0; c2 < 10; c2++){
            float bs = 0;
            #pragma unroll
            for (int i = 0; i < 5; i++) bs += fcb[i * 10 + c2];
            lg[c2] += bs;
        }
        float mx = lg[0];
        #pragma unroll
        for (int c2 = 1; c2 < 10; c2++) mx = fmaxf(mx, lg[c2]);
        float se = 0;
        #pragma unroll
        for (int c2 = 0; c2 < 10; c2++) se += expf(lg[c2] - mx);
        float lse = mx + logf(se);
        #pragma unroll
        for (int c2 = 0; c2 < 10; c2++) out[g * 10 + c2] = lg[c2] - lse;
    }
}

// ---------------- launch ----------------

extern "C" void kernel_launch(void* const* d_in, const int* in_sizes, int n_in,
                              void* d_out, int out_size, void* d_ws, size_t ws_size,
                              hipStream_t stream){
    (void)in_sizes; (void)n_in; (void)out_size; (void)ws_size;
    const float* x     = (const float*)d_in[0];
    const int*   ei    = (const int*)d_in[1];
    const int*   batch = (const int*)d_in[2];
    const float* cW1   = (const float*)d_in[4];
    const float* cb1   = (const float*)d_in[5];
    const float* cbng  = (const float*)d_in[6];
    const float* cbnb  = (const float*)d_in[7];
    const float* cW2   = (const float*)d_in[8];
    const float* cb2   = (const float*)d_in[9];
    const float* bng   = (const float*)d_in[10];
    const float* bnb   = (const float*)d_in[11];
    const float* fcW   = (const float*)d_in[12];
    const float* fcb   = (const float*)d_in[13];

    char* base = (char*)d_ws;
    size_t off = 0;
    auto alloc = [&](size_t bytes) -> void* {
        void* p = base + off;
        off = (off + bytes + 255) & ~(size_t)255;
        return p;
    };
    unsigned*       hB     = (unsigned*)alloc((size_t)NN * 64 * 4);
    unsigned*       zA     = (unsigned*)alloc((size_t)NN * 64 * 4);
    unsigned*       zB     = (unsigned*)alloc((size_t)NN * 64 * 4);
    unsigned short* Wtall  = (unsigned short*)alloc(8 * 16384 * 2);
    int*            ssort  = (int*)alloc((size_t)EE * 4);
    int*            rp     = (int*)alloc((NN + 1) * 4);
    int*            gstart = (int*)alloc((GG + 1) * 4);
    int*            bucketCnt  = (int*)alloc(NB * 4);
    int*            bucketBase = (int*)alloc((NB + 1) * 4);
    int*            bucketCur  = (int*)alloc(NB * 4);
    float*          pooled = (float*)alloc((size_t)5 * GD * 4);
    float*          stats1 = (float*)alloc(256 * 4);
    float*          stats2 = (float*)alloc(256 * 4);
    unsigned*       binned = (unsigned*)zB;   // alias: binned only used before layer loop

    zero_k<<<1, 256, 0, stream>>>(bucketCnt, NB);
    convx_k<<<NN * 64 / 256, 256, 0, stream>>>((const float2*)x, hB);
    wprep_k<<<512, 256, 0, stream>>>(cW1, cW2, Wtall);
    bhist_k<<<(EE + BK_EDGES - 1) / BK_EDGES, 256, 0, stream>>>(ei + EE, bucketCnt);
    bscan_k<<<1, 256, 0, stream>>>(bucketCnt, bucketBase, bucketCur, rp);
    gsearch_k<<<3, 256, 0, stream>>>(batch, gstart);
    binA_k<<<(EE + BK_EDGES - 1) / BK_EDGES, 256, 0, stream>>>(ei, ei + EE, bucketCur, binned);
    binB_k<<<NB, 256, 0, stream>>>(binned, bucketBase, rp, ssort);
    poolx_k<<<GG, 256, 0, stream>>>(x, gstart, pooled);

    const int gemmGrid = 2 * ((NN + 127) / 128);
    for (int i = 0; i < LLAY; i++){
        agg_k<<<NN / 4, 256, 0, stream>>>(hB, rp, ssort, zA, stats1);
        gemm_k<0><<<gemmGrid, 256, 0, stream>>>(zA, Wtall + i * 16384, cb1 + i * 128,
                                                (unsigned short*)zB,
                                                nullptr, nullptr, nullptr, stats1, stats2);
        gemm_k<1><<<gemmGrid, 256, 0, stream>>>(zB, Wtall + (4 + i) * 16384, cb2 + i * 128,
                                                (unsigned short*)zA,
                                                stats1, cbng + i * 128, cbnb + i * 128, stats2, nullptr);
        ewpool_k<<<GG, 256, 0, stream>>>(zA, stats2, bng + i * 128, bnb + i * 128,
                                         gstart, hB, pooled + (size_t)(i + 1) * GD);
    }
    final_k<<<GG, 64, 0, stream>>>(pooled, fcW, fcb, (float*)d_out);
}